// Round 12
// baseline (77.497 us; speedup 1.0000x reference)
//
#include <hip/hip_runtime.h>
#include <hip/hip_fp16.h>
#include <math.h>

// Problem constants (match reference)
#define NN 256
#define GSZ 512
#define GG (GSZ * GSZ)
#define BC 16            // B*C
#define MM 65536
#define ALPHA_C 14.04f   // 2.34 * W
#define WKER 6
#define PI_F 3.14159265358979f
#define RC2 0.70710678118654752f
#define KSCALE 81.48733086305042f  // GSZ / (2*pi)

// fp16 spectrum scaling (see r10 post-mortem): pack Xk*2^24, fold 2^-24 into w0.
#define SSCALE 16777216.0f                 // 2^24
#define INV_SSCALE 5.9604644775390625e-8f  // 2^-24 (exact)

// Gather tiling: 16x16 cells, 1024 tiles, ~64 pts/tile
#define CAP 160          // bucket capacity (mean 64, sd 8 -> +12 sigma)
#define TRW 21           // stencil region rows/cols per tile (16 + 5)
#define TPITCH 23        // LDS row pitch in half2 (odd -> all 32 banks)
#define PLANE (TRW * TPITCH)     // 483 half2 per bc plane
#define QPL 4            // planes (bc images) per gather block
#define NPQ (QPL * TRW * TRW)    // 1764 half2 staged per block

// fp16 spectrum plane: lives in rows [128,384) of each fp32 grid plane.
__device__ __forceinline__ __half2* gh_plane(float2* grid, int bc) {
    return (__half2*)((char*)grid + (size_t)bc * (GG * 8) + 524288);
}
__device__ __forceinline__ const __half2* gh_plane_c(const float2* grid, int bc) {
    return (const __half2*)((const char*)grid + (size_t)bc * (GG * 8) + 524288);
}

// ---------------- device math helpers ----------------

__device__ __forceinline__ float bessel_i0(float x) {
    if (x < 3.75f) {
        float t = x * (1.0f / 3.75f);
        float t2 = t * t;
        return 1.0f + t2 * (3.5156229f + t2 * (3.0899424f + t2 * (1.2067492f +
                     t2 * (0.2659732f + t2 * (0.0360768f + t2 * 0.0045813f)))));
    } else {
        float t = 3.75f / x;
        float p = 0.39894228f + t * (0.01328592f + t * (0.00225319f + t * (-0.00157565f +
                  t * (0.00916281f + t * (-0.02057706f + t * (0.02635537f +
                  t * (-0.01647633f + t * 0.00392377f)))))));
        return p * __expf(x) * rsqrtf(x);
    }
}

__device__ __forceinline__ float kb_weight(float d) {
    float r = d * (2.0f / (float)WKER);
    float u = 1.0f - r * r;
    if (u <= 0.0f) return 0.0f;
    return bessel_i0(ALPHA_C * sqrtf(u)) * (1.0f / (float)WKER);
}

__device__ __forceinline__ float kb_ft_inv(float t) {
    float a = PI_F * (float)WKER * t;
    float s2 = ALPHA_C * ALPHA_C - a * a;
    float z = sqrtf(fabsf(s2)) + 1e-12f;
    float sh = 0.5f * (__expf(z) - __expf(-z));
    return z / sh;
}

__device__ __forceinline__ void cmul(float& zr, float& zi, float wr, float wi) {
    float r = zr * wr - zi * wi;
    zi = zr * wi + zi * wr;
    zr = r;
}

// ---------------- radix-8 stage (unchanged) ----------

template <int L>
__device__ __forceinline__ void radix8_stage(float* pr, float* pi_, int j) {
    int pos = j & (L - 1);
    int base = (j - pos) * 8 + pos;
    float ar[8], ai[8];
#pragma unroll
    for (int r = 0; r < 8; ++r) {
        int idx = base + r * L;
        int ph = idx + (idx >> 3);
        ar[r] = pr[ph];
        ai[r] = pi_[ph];
    }
    if (L > 1) {
        float th = (float)pos * (-PI_F / (4.0f * (float)L));
        float s1, c1;
        __sincosf(th, &s1, &c1);
        float wr = c1, wi = s1;
#pragma unroll
        for (int r = 1; r < 8; ++r) {
            cmul(ar[r], ai[r], wr, wi);
            float nr = wr * c1 - wi * s1;
            wi = wr * s1 + wi * c1;
            wr = nr;
        }
    }
    float s0r = ar[0] + ar[4], s0i = ai[0] + ai[4];
    float d0r = ar[0] - ar[4], d0i = ai[0] - ai[4];
    float s1r = ar[2] + ar[6], s1i = ai[2] + ai[6];
    float d1r = ar[2] - ar[6], d1i = ai[2] - ai[6];
    float E0r = s0r + s1r, E0i = s0i + s1i;
    float E2r = s0r - s1r, E2i = s0i - s1i;
    float E1r = d0r + d1i, E1i = d0i - d1r;
    float E3r = d0r - d1i, E3i = d0i + d1r;
    float u0r = ar[1] + ar[5], u0i = ai[1] + ai[5];
    float v0r = ar[1] - ar[5], v0i = ai[1] - ai[5];
    float u1r = ar[3] + ar[7], u1i = ai[3] + ai[7];
    float v1r = ar[3] - ar[7], v1i = ai[3] - ai[7];
    float O0r = u0r + u1r, O0i = u0i + u1i;
    float O2r = u0r - u1r, O2i = u0i - u1i;
    float O1r = v0r + v1i, O1i = v0i - v1r;
    float O3r = v0r - v1i, O3i = v0i + v1r;
    float t1r = RC2 * (O1r + O1i), t1i = RC2 * (O1i - O1r);
    float t2r = O2i,               t2i = -O2r;
    float t3r = RC2 * (O3i - O3r), t3i = -RC2 * (O3r + O3i);
    float xr[8], xi[8];
    xr[0] = E0r + O0r; xi[0] = E0i + O0i;
    xr[4] = E0r - O0r; xi[4] = E0i - O0i;
    xr[1] = E1r + t1r; xi[1] = E1i + t1i;
    xr[5] = E1r - t1r; xi[5] = E1i - t1i;
    xr[2] = E2r + t2r; xi[2] = E2i + t2i;
    xr[6] = E2r - t2r; xi[6] = E2i - t2i;
    xr[3] = E3r + t3r; xi[3] = E3i + t3i;
    xr[7] = E3r - t3r; xi[7] = E3i - t3i;
#pragma unroll
    for (int q = 0; q < 8; ++q) {
        int idx = base + q * L;
        int ph = idx + (idx >> 3);
        pr[ph] = xr[q];
        pi_[ph] = xi[q];
    }
}

// ---------------- FFT kernels (unchanged from round 11) ----------------

#define LDSP 576
__global__ void __launch_bounds__(256) k_fft_row(const float* __restrict__ x,
                                                 float2* __restrict__ grid) {
    __shared__ float re[4][LDSP], im[4][LDSP];
    int b = blockIdx.x;
    int t = threadIdx.x;
    int w = t >> 6;
    int l = t & 63;
    int rg = (b & 63) * 4 + w;
    int bc = b >> 6;
    int r = (rg < 128) ? rg : rg + 256;
    int r_img = rg ^ 128;
    float scx = kb_ft_inv((float)(r_img - 128) * (1.0f / (float)GSZ));
    const float* xrow = x + ((size_t)bc * NN + (size_t)r_img) * NN;
#pragma unroll
    for (int e = 0; e < 8; ++e) {
        int i = e * 64 + l;
        float v = 0.0f;
        if (i < 128 || i >= 384) {
            int y = (i + 128) & (GSZ - 1);
            float scy = kb_ft_inv((float)(y - 128) * (1.0f / (float)GSZ));
            v = xrow[y] * scx * scy;
        }
        int rev = (l & 7) * 64 + (l >> 3) * 8 + e;
        int ph = rev + (rev >> 3);
        re[w][ph] = v;
        im[w][ph] = 0.0f;
    }
    __syncthreads();
    radix8_stage<1>(re[w], im[w], l);
    __syncthreads();
    radix8_stage<8>(re[w], im[w], l);
    __syncthreads();
    radix8_stage<64>(re[w], im[w], l);
    __syncthreads();
    size_t gbase = (size_t)bc * GG + (size_t)r * GSZ;
#pragma unroll
    for (int e = 0; e < 8; ++e) {
        int k = e * 64 + l;
        int ph = k + (k >> 3);
        grid[gbase + k] = make_float2(re[w][ph], im[w][ph]);
    }
}

#define CSTR 577
__global__ void __launch_bounds__(256) k_fft_col(float2* __restrict__ grid) {
    __shared__ float re[16][CSTR], im[16][CSTR];
    int b = blockIdx.x;
    int bc = b >> 5;
    int c0 = (b & 31) << 4;
    size_t base = (size_t)bc * GG + (size_t)c0;
    int t = threadIdx.x;
#pragma unroll
    for (int it = 0; it < 32; ++it) {
        int idx = it * 256 + t;
        int row = idx >> 4, col = idx & 15;
        float2 v = make_float2(0.0f, 0.0f);
        if (row < 128 || row >= 384)
            v = grid[base + (size_t)row * GSZ + col];
        int rev = (row & 7) * 64 + ((row >> 3) & 7) * 8 + (row >> 6);
        int ph = rev + (rev >> 3);
        re[col][ph] = v.x;
        im[col][ph] = v.y;
    }
    __syncthreads();
    int col = t & 15, jg = t >> 4;
#pragma unroll
    for (int k = 0; k < 4; ++k) radix8_stage<1>(re[col], im[col], jg + 16 * k);
    __syncthreads();
#pragma unroll
    for (int k = 0; k < 4; ++k) radix8_stage<8>(re[col], im[col], jg + 16 * k);
    __syncthreads();
#pragma unroll
    for (int k = 0; k < 4; ++k) radix8_stage<64>(re[col], im[col], jg + 16 * k);
    __syncthreads();
    __half2* ghp = gh_plane(grid, bc);
#pragma unroll
    for (int it = 0; it < 32; ++it) {
        int idx = it * 256 + t;
        int row = idx >> 4, c = idx & 15;
        int ph = row + (row >> 3);
        ghp[(size_t)row * GSZ + c0 + c] = __float22half2_rn(
            make_float2(re[c][ph] * SSCALE, im[c][ph] * SSCALE));
    }
}

// ---------------- binning ----------------

__global__ void k_bin(const float* __restrict__ kt, unsigned* __restrict__ cnt,
                      unsigned short* __restrict__ ubuf) {
    int m = blockIdx.x * blockDim.x + threadIdx.x;
    float tmx = kt[m] * KSCALE;
    float tmy = kt[MM + m] * KSCALE;
    int ibx = (int)floorf(tmx) & (GSZ - 1);
    int iby = (int)floorf(tmy) & (GSZ - 1);
    int tile = ((ibx >> 4) << 5) | (iby >> 4);
    unsigned slot = atomicAdd(&cnt[tile], 1u);
    if (slot < CAP) ubuf[(size_t)tile * CAP + slot] = (unsigned short)m;
}

// ---------------- fine-grained fp16 tile gather ----------------
// 4096 blocks x 128 threads: block = (tile, bc-quad). Stage only 4 planes
// (7.7 KB; LDS total 16.7 KB -> ~9 blocks/CU, ~18 waves/CU). One barrier.
// Wave g covers bc pair (2g, 2g+1) of the quad; lanes stripe points.

__global__ void __launch_bounds__(128) k_gather_tile(
    const float2* __restrict__ grid, const float* __restrict__ kt,
    const unsigned* __restrict__ cnt, const unsigned short* __restrict__ ubuf,
    float2* __restrict__ out) {
    __shared__ __half2 ldsh[QPL * PLANE];   // 7728 B
    __shared__ float wts[CAP][13];          // 8320 B
    __shared__ unsigned lxy[CAP];           // 640 B   (total 16688 B)
    int bid = blockIdx.x;
    int b = ((bid & 7) << 9) | (bid >> 3);  // bijective XCD swizzle (4096 = 8*512)
    int tile = b >> 2;
    int quad = b & 3;
    int bc0 = quad * QPL;
    int tx0 = (tile >> 5) << 4;
    int ty0 = (tile & 31) << 4;
    int t = threadIdx.x;
    // stage 4 planes (global -> LDS), compiler pipelines the 14 loads
#pragma unroll
    for (int k = 0; k < 14; ++k) {
        int idx = t + (k << 7);
        if (idx < NPQ) {
            int p = idx / (TRW * TRW);
            int rem = idx - p * (TRW * TRW);
            int r = rem / TRW;
            int c = rem - r * TRW;
            int row = (tx0 - 2 + r) & (GSZ - 1);
            int col = (ty0 - 2 + c) & (GSZ - 1);
            ldsh[p * PLANE + r * TPITCH + c] =
                gh_plane_c(grid, bc0 + p)[(size_t)row * GSZ + col];
        }
    }
    int n = (int)cnt[tile];
    if (n > CAP) n = CAP;
    // weights (both waves, stride 128; redundant across quads -> cheap VALU)
    for (int p = t; p < n; p += 128) {
        int m = (int)ubuf[(size_t)tile * CAP + p];
        float tmx = kt[m] * KSCALE;
        float tmy = kt[MM + m] * KSCALE;
        float bx = floorf(tmx), by = floorf(tmy);
#pragma unroll
        for (int o = 0; o < 6; ++o) {
            float offv = (float)(o - 2);
            wts[p][o]     = kb_weight(tmx - (bx + offv)) * INV_SSCALE;
            wts[p][6 + o] = kb_weight(tmy - (by + offv));
        }
        int lx = (int)bx & 15;
        int ly = (int)by & 15;
        lxy[p] = ((unsigned)m << 8) | (unsigned)(lx << 4) | (unsigned)ly;
    }
    __syncthreads();
    int g = t >> 6;                         // wave -> plane pair (2g, 2g+1)
    int baseA = (2 * g) * PLANE;
    int baseB = baseA + PLANE;
    int bcA = bc0 + 2 * g, bcB = bcA + 1;
    for (int s = (t & 63); s < n; s += 64) {
        unsigned lc = lxy[s];
        int m = (int)(lc >> 8);
        int lx = (int)((lc >> 4) & 15u);
        int ly = (int)(lc & 15u);
        float w0v[6], w1v[6];
#pragma unroll
        for (int o = 0; o < 6; ++o) {
            w0v[o] = wts[s][o];
            w1v[o] = wts[s][6 + o];
        }
        int off0 = lx * TPITCH + ly;
        float arA = 0.f, aiA = 0.f, arB = 0.f, aiB = 0.f;
#pragma unroll
        for (int ii = 0; ii < 6; ++ii) {
            float wi = w0v[ii];
            int rowoff = off0 + ii * TPITCH;
#pragma unroll
            for (int j = 0; j < 6; ++j) {
                float wv = wi * w1v[j];
                int o = rowoff + j;
                float2 vA = __half22float2(ldsh[baseA + o]);
                float2 vB = __half22float2(ldsh[baseB + o]);
                arA = fmaf(wv, vA.x, arA);
                aiA = fmaf(wv, vA.y, aiA);
                arB = fmaf(wv, vB.x, arB);
                aiB = fmaf(wv, vB.y, aiB);
            }
        }
        out[(size_t)bcA * MM + m] = make_float2(arA, aiA);
        out[(size_t)bcB * MM + m] = make_float2(arB, aiB);
    }
}

// Fallback gather (reads fp16 spectrum) if ws is too small for binning.
__global__ void k_gather(const float2* __restrict__ grid, const float* __restrict__ kt,
                         float2* __restrict__ out) {
    int tid = blockIdx.x * blockDim.x + threadIdx.x;
    int m = tid & (MM - 1);
    int bc = tid >> 16;
    float tmx = kt[m] * KSCALE;
    float tmy = kt[MM + m] * KSCALE;
    float bx = floorf(tmx), by = floorf(tmy);
    int ibx = (int)bx, iby = (int)by;
    float w0[6], w1[6];
    int ix[6], iy[6];
#pragma unroll
    for (int o = 0; o < 6; ++o) {
        float offv = (float)(o - 2);
        w0[o] = kb_weight(tmx - (bx + offv)) * INV_SSCALE;
        w1[o] = kb_weight(tmy - (by + offv));
        ix[o] = (ibx + (o - 2) + GSZ) & (GSZ - 1);
        iy[o] = (iby + (o - 2) + GSZ) & (GSZ - 1);
    }
    const __half2* img = gh_plane_c(grid, bc);
    float ar = 0.0f, ai = 0.0f;
#pragma unroll
    for (int i = 0; i < 6; ++i) {
        const __half2* rowp = img + (size_t)ix[i] * GSZ;
        float wi = w0[i];
#pragma unroll
        for (int j = 0; j < 6; ++j) {
            float2 v = __half22float2(rowp[iy[j]]);
            float wv = wi * w1[j];
            ar = fmaf(wv, v.x, ar);
            ai = fmaf(wv, v.y, ai);
        }
    }
    out[(size_t)bc * MM + m] = make_float2(ar, ai);
}

// ---------------- launch ----------------

extern "C" void kernel_launch(void* const* d_in, const int* in_sizes, int n_in,
                              void* d_out, int out_size, void* d_ws, size_t ws_size,
                              hipStream_t stream) {
    const float* x = (const float*)d_in[0];
    const float* kt = (const float*)d_in[1];
    float2* out = (float2*)d_out;
    char* ws = (char*)d_ws;

    const size_t GRID_BYTES = (size_t)BC * GG * sizeof(float2);      // 33.55 MB
    const size_t CNT_BYTES = 1024 * sizeof(unsigned);                // 4 KB
    const size_t UBUF_BYTES = (size_t)1024 * CAP * sizeof(unsigned short); // 320 KB
    float2* grid = (float2*)ws;
    unsigned* cnt = (unsigned*)(ws + GRID_BYTES);
    unsigned short* ubuf = (unsigned short*)(ws + GRID_BYTES + CNT_BYTES);
    const size_t NEED = GRID_BYTES + CNT_BYTES + UBUF_BYTES;

    if (ws_size >= NEED) {
        hipMemsetAsync(cnt, 0, CNT_BYTES, stream);
        k_bin<<<MM / 256, 256, 0, stream>>>(kt, cnt, ubuf);
        k_fft_row<<<BC * 64, 256, 0, stream>>>(x, grid);
        k_fft_col<<<BC * (GSZ / 16), 256, 0, stream>>>(grid);
        k_gather_tile<<<4096, 128, 0, stream>>>(grid, kt, cnt, ubuf, out);
    } else {
        k_fft_row<<<BC * 64, 256, 0, stream>>>(x, grid);
        k_fft_col<<<BC * (GSZ / 16), 256, 0, stream>>>(grid);
        k_gather<<<(BC * MM) / 256, 256, 0, stream>>>(grid, kt, out);
    }
}

// Round 13
// 75.910 us; speedup vs baseline: 1.0209x; 1.0209x over previous
//
#include <hip/hip_runtime.h>
#include <hip/hip_fp16.h>
#include <math.h>

// Problem constants (match reference)
#define NN 256
#define GSZ 512
#define GG (GSZ * GSZ)
#define BC 16            // B*C
#define MM 65536
#define ALPHA_C 14.04f   // 2.34 * W
#define WKER 6
#define PI_F 3.14159265358979f
#define RC2 0.70710678118654752f
#define KSCALE 81.48733086305042f  // GSZ / (2*pi)

// fp16 spectrum scaling (see r10 post-mortem): pack Xk*2^24, fold 2^-24 into w0.
#define SSCALE 16777216.0f                 // 2^24
#define INV_SSCALE 5.9604644775390625e-8f  // 2^-24 (exact)

// Gather tiling: 16x16 cells, 1024 tiles, ~64 pts/tile
#define CAP 160          // bucket capacity (mean 64, sd 8 -> +12 sigma)
#define TRW 21           // stencil region rows/cols per tile (16 + 5)
#define TPITCH 23        // LDS row pitch in half2 (odd -> all 32 banks)
#define PLANE (TRW * TPITCH)     // 483 half2 per bc plane
#define QPL 4            // planes (bc images) per gather block
#define NPQ (QPL * TRW * TRW)    // 1764 half2 staged per block

// fp16 spectrum plane: lives in rows [128,384) of each fp32 grid plane.
__device__ __forceinline__ __half2* gh_plane(float2* grid, int bc) {
    return (__half2*)((char*)grid + (size_t)bc * (GG * 8) + 524288);
}
__device__ __forceinline__ const __half2* gh_plane_c(const float2* grid, int bc) {
    return (const __half2*)((const char*)grid + (size_t)bc * (GG * 8) + 524288);
}

// ---------------- device math helpers ----------------

__device__ __forceinline__ float bessel_i0(float x) {
    if (x < 3.75f) {
        float t = x * (1.0f / 3.75f);
        float t2 = t * t;
        return 1.0f + t2 * (3.5156229f + t2 * (3.0899424f + t2 * (1.2067492f +
                     t2 * (0.2659732f + t2 * (0.0360768f + t2 * 0.0045813f)))));
    } else {
        float t = 3.75f / x;
        float p = 0.39894228f + t * (0.01328592f + t * (0.00225319f + t * (-0.00157565f +
                  t * (0.00916281f + t * (-0.02057706f + t * (0.02635537f +
                  t * (-0.01647633f + t * 0.00392377f)))))));
        return p * __expf(x) * rsqrtf(x);
    }
}

__device__ __forceinline__ float kb_weight(float d) {
    float r = d * (2.0f / (float)WKER);
    float u = 1.0f - r * r;
    if (u <= 0.0f) return 0.0f;
    return bessel_i0(ALPHA_C * sqrtf(u)) * (1.0f / (float)WKER);
}

__device__ __forceinline__ float kb_ft_inv(float t) {
    float a = PI_F * (float)WKER * t;
    float s2 = ALPHA_C * ALPHA_C - a * a;
    float z = sqrtf(fabsf(s2)) + 1e-12f;
    float sh = 0.5f * (__expf(z) - __expf(-z));
    return z / sh;
}

__device__ __forceinline__ void cmul(float& zr, float& zi, float wr, float wi) {
    float r = zr * wr - zi * wi;
    zi = zr * wi + zi * wr;
    zr = r;
}

// ---------------- radix-8 stage (unchanged) ----------

template <int L>
__device__ __forceinline__ void radix8_stage(float* pr, float* pi_, int j) {
    int pos = j & (L - 1);
    int base = (j - pos) * 8 + pos;
    float ar[8], ai[8];
#pragma unroll
    for (int r = 0; r < 8; ++r) {
        int idx = base + r * L;
        int ph = idx + (idx >> 3);
        ar[r] = pr[ph];
        ai[r] = pi_[ph];
    }
    if (L > 1) {
        float th = (float)pos * (-PI_F / (4.0f * (float)L));
        float s1, c1;
        __sincosf(th, &s1, &c1);
        float wr = c1, wi = s1;
#pragma unroll
        for (int r = 1; r < 8; ++r) {
            cmul(ar[r], ai[r], wr, wi);
            float nr = wr * c1 - wi * s1;
            wi = wr * s1 + wi * c1;
            wr = nr;
        }
    }
    float s0r = ar[0] + ar[4], s0i = ai[0] + ai[4];
    float d0r = ar[0] - ar[4], d0i = ai[0] - ai[4];
    float s1r = ar[2] + ar[6], s1i = ai[2] + ai[6];
    float d1r = ar[2] - ar[6], d1i = ai[2] - ai[6];
    float E0r = s0r + s1r, E0i = s0i + s1i;
    float E2r = s0r - s1r, E2i = s0i - s1i;
    float E1r = d0r + d1i, E1i = d0i - d1r;
    float E3r = d0r - d1i, E3i = d0i + d1r;
    float u0r = ar[1] + ar[5], u0i = ai[1] + ai[5];
    float v0r = ar[1] - ar[5], v0i = ai[1] - ai[5];
    float u1r = ar[3] + ar[7], u1i = ai[3] + ai[7];
    float v1r = ar[3] - ar[7], v1i = ai[3] - ai[7];
    float O0r = u0r + u1r, O0i = u0i + u1i;
    float O2r = u0r - u1r, O2i = u0i - u1i;
    float O1r = v0r + v1i, O1i = v0i - v1r;
    float O3r = v0r - v1i, O3i = v0i + v1r;
    float t1r = RC2 * (O1r + O1i), t1i = RC2 * (O1i - O1r);
    float t2r = O2i,               t2i = -O2r;
    float t3r = RC2 * (O3i - O3r), t3i = -RC2 * (O3r + O3i);
    float xr[8], xi[8];
    xr[0] = E0r + O0r; xi[0] = E0i + O0i;
    xr[4] = E0r - O0r; xi[4] = E0i - O0i;
    xr[1] = E1r + t1r; xi[1] = E1i + t1i;
    xr[5] = E1r - t1r; xi[5] = E1i - t1i;
    xr[2] = E2r + t2r; xi[2] = E2i + t2i;
    xr[6] = E2r - t2r; xi[6] = E2i - t2i;
    xr[3] = E3r + t3r; xi[3] = E3i + t3i;
    xr[7] = E3r - t3r; xi[7] = E3i - t3i;
#pragma unroll
    for (int q = 0; q < 8; ++q) {
        int idx = base + q * L;
        int ph = idx + (idx >> 3);
        pr[ph] = xr[q];
        pi_[ph] = xi[q];
    }
}

// ---------------- fused row-FFT + binning ----------------
// Blocks [0, BC*64): row FFTs (4 rows each). Blocks [BC*64, BC*64+256): binning.

#define LDSP 576
#define ROWBLK (BC * 64)
__global__ void __launch_bounds__(256) k_fft_row_bin(
    const float* __restrict__ x, float2* __restrict__ grid,
    const float* __restrict__ kt, unsigned* __restrict__ cnt,
    unsigned short* __restrict__ ubuf) {
    __shared__ float re[4][LDSP], im[4][LDSP];
    int b = blockIdx.x;
    int t = threadIdx.x;
    if (b >= ROWBLK) {
        // ---- binning part ----
        int m = (b - ROWBLK) * 256 + t;
        float tmx = kt[m] * KSCALE;
        float tmy = kt[MM + m] * KSCALE;
        int ibx = (int)floorf(tmx) & (GSZ - 1);
        int iby = (int)floorf(tmy) & (GSZ - 1);
        int tile = ((ibx >> 4) << 5) | (iby >> 4);
        unsigned slot = atomicAdd(&cnt[tile], 1u);
        if (slot < CAP) ubuf[(size_t)tile * CAP + slot] = (unsigned short)m;
        return;
    }
    int w = t >> 6;
    int l = t & 63;
    int rg = (b & 63) * 4 + w;
    int bc = b >> 6;
    int r = (rg < 128) ? rg : rg + 256;
    int r_img = rg ^ 128;
    float scx = kb_ft_inv((float)(r_img - 128) * (1.0f / (float)GSZ));
    const float* xrow = x + ((size_t)bc * NN + (size_t)r_img) * NN;
#pragma unroll
    for (int e = 0; e < 8; ++e) {
        int i = e * 64 + l;
        float v = 0.0f;
        if (i < 128 || i >= 384) {
            int y = (i + 128) & (GSZ - 1);
            float scy = kb_ft_inv((float)(y - 128) * (1.0f / (float)GSZ));
            v = xrow[y] * scx * scy;
        }
        int rev = (l & 7) * 64 + (l >> 3) * 8 + e;
        int ph = rev + (rev >> 3);
        re[w][ph] = v;
        im[w][ph] = 0.0f;
    }
    __syncthreads();
    radix8_stage<1>(re[w], im[w], l);
    __syncthreads();
    radix8_stage<8>(re[w], im[w], l);
    __syncthreads();
    radix8_stage<64>(re[w], im[w], l);
    __syncthreads();
    size_t gbase = (size_t)bc * GG + (size_t)r * GSZ;
#pragma unroll
    for (int e = 0; e < 8; ++e) {
        int k = e * 64 + l;
        int ph = k + (k >> 3);
        grid[gbase + k] = make_float2(re[w][ph], im[w][ph]);
    }
}

// ---------------- column FFT (unchanged from round 12) ----------------

#define CSTR 577
__global__ void __launch_bounds__(256) k_fft_col(float2* __restrict__ grid) {
    __shared__ float re[16][CSTR], im[16][CSTR];
    int b = blockIdx.x;
    int bc = b >> 5;
    int c0 = (b & 31) << 4;
    size_t base = (size_t)bc * GG + (size_t)c0;
    int t = threadIdx.x;
#pragma unroll
    for (int it = 0; it < 32; ++it) {
        int idx = it * 256 + t;
        int row = idx >> 4, col = idx & 15;
        float2 v = make_float2(0.0f, 0.0f);
        if (row < 128 || row >= 384)
            v = grid[base + (size_t)row * GSZ + col];
        int rev = (row & 7) * 64 + ((row >> 3) & 7) * 8 + (row >> 6);
        int ph = rev + (rev >> 3);
        re[col][ph] = v.x;
        im[col][ph] = v.y;
    }
    __syncthreads();
    int col = t & 15, jg = t >> 4;
#pragma unroll
    for (int k = 0; k < 4; ++k) radix8_stage<1>(re[col], im[col], jg + 16 * k);
    __syncthreads();
#pragma unroll
    for (int k = 0; k < 4; ++k) radix8_stage<8>(re[col], im[col], jg + 16 * k);
    __syncthreads();
#pragma unroll
    for (int k = 0; k < 4; ++k) radix8_stage<64>(re[col], im[col], jg + 16 * k);
    __syncthreads();
    __half2* ghp = gh_plane(grid, bc);
#pragma unroll
    for (int it = 0; it < 32; ++it) {
        int idx = it * 256 + t;
        int row = idx >> 4, c = idx & 15;
        int ph = row + (row >> 3);
        ghp[(size_t)row * GSZ + c0 + c] = __float22half2_rn(
            make_float2(re[c][ph] * SSCALE, im[c][ph] * SSCALE));
    }
}

// ---------------- lean fp16 tile gather: register weights, planes-only LDS ---
// 4096 blocks x 128 threads, block = (tile, bc-quad). LDS = 4 planes (7.7 KB)
// -> full 32-wave/CU residency (entire grid resident). Each lane owns point s:
// reads ubuf/kt directly, computes its 12 weights in registers (bit-identical
// to the previous shared-LDS version), then 36 taps x 2 planes.

__global__ void __launch_bounds__(128, 6) k_gather_tile(
    const float2* __restrict__ grid, const float* __restrict__ kt,
    const unsigned* __restrict__ cnt, const unsigned short* __restrict__ ubuf,
    float2* __restrict__ out) {
    __shared__ __half2 ldsh[QPL * PLANE];   // 7728 B (total LDS)
    int bid = blockIdx.x;
    int b = ((bid & 7) << 9) | (bid >> 3);  // bijective XCD swizzle (4096 = 8*512)
    int tile = b >> 2;
    int quad = b & 3;
    int bc0 = quad * QPL;
    int tx0 = (tile >> 5) << 4;
    int ty0 = (tile & 31) << 4;
    int t = threadIdx.x;
#pragma unroll
    for (int k = 0; k < 14; ++k) {
        int idx = t + (k << 7);
        if (idx < NPQ) {
            int p = idx / (TRW * TRW);
            int rem = idx - p * (TRW * TRW);
            int r = rem / TRW;
            int c = rem - r * TRW;
            int row = (tx0 - 2 + r) & (GSZ - 1);
            int col = (ty0 - 2 + c) & (GSZ - 1);
            ldsh[p * PLANE + r * TPITCH + c] =
                gh_plane_c(grid, bc0 + p)[(size_t)row * GSZ + col];
        }
    }
    int n = (int)cnt[tile];
    if (n > CAP) n = CAP;
    __syncthreads();
    int g = t >> 6;                         // wave -> plane pair (2g, 2g+1)
    int baseA = (2 * g) * PLANE;
    int baseB = baseA + PLANE;
    int bcA = bc0 + 2 * g, bcB = bcA + 1;
    for (int s = (t & 63); s < n; s += 64) {
        int m = (int)ubuf[(size_t)tile * CAP + s];
        float tmx = kt[m] * KSCALE;
        float tmy = kt[MM + m] * KSCALE;
        float bx = floorf(tmx), by = floorf(tmy);
        float w0v[6], w1v[6];
#pragma unroll
        for (int o = 0; o < 6; ++o) {
            float offv = (float)(o - 2);
            w0v[o] = kb_weight(tmx - (bx + offv)) * INV_SSCALE;
            w1v[o] = kb_weight(tmy - (by + offv));
        }
        int lx = (int)bx & 15;
        int ly = (int)by & 15;
        int off0 = lx * TPITCH + ly;
        float arA = 0.f, aiA = 0.f, arB = 0.f, aiB = 0.f;
#pragma unroll
        for (int ii = 0; ii < 6; ++ii) {
            float wi = w0v[ii];
            int rowoff = off0 + ii * TPITCH;
#pragma unroll
            for (int j = 0; j < 6; ++j) {
                float wv = wi * w1v[j];
                int o = rowoff + j;
                float2 vA = __half22float2(ldsh[baseA + o]);
                float2 vB = __half22float2(ldsh[baseB + o]);
                arA = fmaf(wv, vA.x, arA);
                aiA = fmaf(wv, vA.y, aiA);
                arB = fmaf(wv, vB.x, arB);
                aiB = fmaf(wv, vB.y, aiB);
            }
        }
        out[(size_t)bcA * MM + m] = make_float2(arA, aiA);
        out[(size_t)bcB * MM + m] = make_float2(arB, aiB);
    }
}

// Fallback gather (reads fp16 spectrum) if ws is too small for binning.
__global__ void k_gather(const float2* __restrict__ grid, const float* __restrict__ kt,
                         float2* __restrict__ out) {
    int tid = blockIdx.x * blockDim.x + threadIdx.x;
    int m = tid & (MM - 1);
    int bc = tid >> 16;
    float tmx = kt[m] * KSCALE;
    float tmy = kt[MM + m] * KSCALE;
    float bx = floorf(tmx), by = floorf(tmy);
    int ibx = (int)bx, iby = (int)by;
    float w0[6], w1[6];
    int ix[6], iy[6];
#pragma unroll
    for (int o = 0; o < 6; ++o) {
        float offv = (float)(o - 2);
        w0[o] = kb_weight(tmx - (bx + offv)) * INV_SSCALE;
        w1[o] = kb_weight(tmy - (by + offv));
        ix[o] = (ibx + (o - 2) + GSZ) & (GSZ - 1);
        iy[o] = (iby + (o - 2) + GSZ) & (GSZ - 1);
    }
    const __half2* img = gh_plane_c(grid, bc);
    float ar = 0.0f, ai = 0.0f;
#pragma unroll
    for (int i = 0; i < 6; ++i) {
        const __half2* rowp = img + (size_t)ix[i] * GSZ;
        float wi = w0[i];
#pragma unroll
        for (int j = 0; j < 6; ++j) {
            float2 v = __half22float2(rowp[iy[j]]);
            float wv = wi * w1[j];
            ar = fmaf(wv, v.x, ar);
            ai = fmaf(wv, v.y, ai);
        }
    }
    out[(size_t)bc * MM + m] = make_float2(ar, ai);
}

// Standalone row FFT for the fallback path (no binning).
__global__ void __launch_bounds__(256) k_fft_row(const float* __restrict__ x,
                                                 float2* __restrict__ grid) {
    __shared__ float re[4][LDSP], im[4][LDSP];
    int b = blockIdx.x;
    int t = threadIdx.x;
    int w = t >> 6;
    int l = t & 63;
    int rg = (b & 63) * 4 + w;
    int bc = b >> 6;
    int r = (rg < 128) ? rg : rg + 256;
    int r_img = rg ^ 128;
    float scx = kb_ft_inv((float)(r_img - 128) * (1.0f / (float)GSZ));
    const float* xrow = x + ((size_t)bc * NN + (size_t)r_img) * NN;
#pragma unroll
    for (int e = 0; e < 8; ++e) {
        int i = e * 64 + l;
        float v = 0.0f;
        if (i < 128 || i >= 384) {
            int y = (i + 128) & (GSZ - 1);
            float scy = kb_ft_inv((float)(y - 128) * (1.0f / (float)GSZ));
            v = xrow[y] * scx * scy;
        }
        int rev = (l & 7) * 64 + (l >> 3) * 8 + e;
        int ph = rev + (rev >> 3);
        re[w][ph] = v;
        im[w][ph] = 0.0f;
    }
    __syncthreads();
    radix8_stage<1>(re[w], im[w], l);
    __syncthreads();
    radix8_stage<8>(re[w], im[w], l);
    __syncthreads();
    radix8_stage<64>(re[w], im[w], l);
    __syncthreads();
    size_t gbase = (size_t)bc * GG + (size_t)r * GSZ;
#pragma unroll
    for (int e = 0; e < 8; ++e) {
        int k = e * 64 + l;
        int ph = k + (k >> 3);
        grid[gbase + k] = make_float2(re[w][ph], im[w][ph]);
    }
}

// ---------------- launch ----------------

extern "C" void kernel_launch(void* const* d_in, const int* in_sizes, int n_in,
                              void* d_out, int out_size, void* d_ws, size_t ws_size,
                              hipStream_t stream) {
    const float* x = (const float*)d_in[0];
    const float* kt = (const float*)d_in[1];
    float2* out = (float2*)d_out;
    char* ws = (char*)d_ws;

    const size_t GRID_BYTES = (size_t)BC * GG * sizeof(float2);      // 33.55 MB
    const size_t CNT_BYTES = 1024 * sizeof(unsigned);                // 4 KB
    const size_t UBUF_BYTES = (size_t)1024 * CAP * sizeof(unsigned short); // 320 KB
    float2* grid = (float2*)ws;
    unsigned* cnt = (unsigned*)(ws + GRID_BYTES);
    unsigned short* ubuf = (unsigned short*)(ws + GRID_BYTES + CNT_BYTES);
    const size_t NEED = GRID_BYTES + CNT_BYTES + UBUF_BYTES;

    if (ws_size >= NEED) {
        hipMemsetAsync(cnt, 0, CNT_BYTES, stream);
        k_fft_row_bin<<<ROWBLK + 256, 256, 0, stream>>>(x, grid, kt, cnt, ubuf);
        k_fft_col<<<BC * (GSZ / 16), 256, 0, stream>>>(grid);
        k_gather_tile<<<4096, 128, 0, stream>>>(grid, kt, cnt, ubuf, out);
    } else {
        k_fft_row<<<BC * 64, 256, 0, stream>>>(x, grid);
        k_fft_col<<<BC * (GSZ / 16), 256, 0, stream>>>(grid);
        k_gather<<<(BC * MM) / 256, 256, 0, stream>>>(grid, kt, out);
    }
}

// Round 14
// 67.646 us; speedup vs baseline: 1.1456x; 1.1222x over previous
//
#include <hip/hip_runtime.h>
#include <hip/hip_fp16.h>
#include <math.h>

// Problem constants (match reference)
#define NN 256
#define GSZ 512
#define GG (GSZ * GSZ)
#define BC 16            // B*C
#define MM 65536
#define ALPHA_C 14.04f   // 2.34 * W
#define WKER 6
#define PI_F 3.14159265358979f
#define RC2 0.70710678118654752f
#define KSCALE 81.48733086305042f  // GSZ / (2*pi)

// fp16 spectrum scaling (r10): pack Xk*2^24; 2^-24 applied to w0 at use (exact).
#define SSCALE 16777216.0f                 // 2^24
#define INV_SSCALE 5.9604644775390625e-8f  // 2^-24 (exact)

// Gather tiling: 16x16 cells, 1024 tiles, ~64 pts/tile
#define CAP 144          // bucket capacity (mean 64, sd 8 -> +10 sigma)
#define TRW 21           // stencil region rows/cols per tile (16 + 5)
#define TPITCH 23        // LDS row pitch in half2 (odd -> all 32 banks)
#define PLANE (TRW * TPITCH)     // 483 half2 per bc plane
#define QPL 4            // planes (bc images) per gather block
#define NPQ (QPL * TRW * TRW)    // 1764 half2 staged per block

// fp16 spectrum plane: lives in rows [128,384) of each fp32 grid plane.
__device__ __forceinline__ __half2* gh_plane(float2* grid, int bc) {
    return (__half2*)((char*)grid + (size_t)bc * (GG * 8) + 524288);
}
__device__ __forceinline__ const __half2* gh_plane_c(const float2* grid, int bc) {
    return (const __half2*)((const char*)grid + (size_t)bc * (GG * 8) + 524288);
}

// ---------------- device math helpers ----------------

__device__ __forceinline__ float bessel_i0(float x) {
    if (x < 3.75f) {
        float t = x * (1.0f / 3.75f);
        float t2 = t * t;
        return 1.0f + t2 * (3.5156229f + t2 * (3.0899424f + t2 * (1.2067492f +
                     t2 * (0.2659732f + t2 * (0.0360768f + t2 * 0.0045813f)))));
    } else {
        float t = 3.75f / x;
        float p = 0.39894228f + t * (0.01328592f + t * (0.00225319f + t * (-0.00157565f +
                  t * (0.00916281f + t * (-0.02057706f + t * (0.02635537f +
                  t * (-0.01647633f + t * 0.00392377f)))))));
        return p * __expf(x) * rsqrtf(x);
    }
}

__device__ __forceinline__ float kb_weight(float d) {
    float r = d * (2.0f / (float)WKER);
    float u = 1.0f - r * r;
    if (u <= 0.0f) return 0.0f;
    return bessel_i0(ALPHA_C * sqrtf(u)) * (1.0f / (float)WKER);
}

__device__ __forceinline__ float kb_ft_inv(float t) {
    float a = PI_F * (float)WKER * t;
    float s2 = ALPHA_C * ALPHA_C - a * a;
    float z = sqrtf(fabsf(s2)) + 1e-12f;
    float sh = 0.5f * (__expf(z) - __expf(-z));
    return z / sh;
}

__device__ __forceinline__ void cmul(float& zr, float& zi, float wr, float wi) {
    float r = zr * wr - zi * wi;
    zi = zr * wi + zi * wr;
    zr = r;
}

// ---------------- radix-8 stage (unchanged) ----------

template <int L>
__device__ __forceinline__ void radix8_stage(float* pr, float* pi_, int j) {
    int pos = j & (L - 1);
    int base = (j - pos) * 8 + pos;
    float ar[8], ai[8];
#pragma unroll
    for (int r = 0; r < 8; ++r) {
        int idx = base + r * L;
        int ph = idx + (idx >> 3);
        ar[r] = pr[ph];
        ai[r] = pi_[ph];
    }
    if (L > 1) {
        float th = (float)pos * (-PI_F / (4.0f * (float)L));
        float s1, c1;
        __sincosf(th, &s1, &c1);
        float wr = c1, wi = s1;
#pragma unroll
        for (int r = 1; r < 8; ++r) {
            cmul(ar[r], ai[r], wr, wi);
            float nr = wr * c1 - wi * s1;
            wi = wr * s1 + wi * c1;
            wr = nr;
        }
    }
    float s0r = ar[0] + ar[4], s0i = ai[0] + ai[4];
    float d0r = ar[0] - ar[4], d0i = ai[0] - ai[4];
    float s1r = ar[2] + ar[6], s1i = ai[2] + ai[6];
    float d1r = ar[2] - ar[6], d1i = ai[2] - ai[6];
    float E0r = s0r + s1r, E0i = s0i + s1i;
    float E2r = s0r - s1r, E2i = s0i - s1i;
    float E1r = d0r + d1i, E1i = d0i - d1r;
    float E3r = d0r - d1i, E3i = d0i + d1r;
    float u0r = ar[1] + ar[5], u0i = ai[1] + ai[5];
    float v0r = ar[1] - ar[5], v0i = ai[1] - ai[5];
    float u1r = ar[3] + ar[7], u1i = ai[3] + ai[7];
    float v1r = ar[3] - ar[7], v1i = ai[3] - ai[7];
    float O0r = u0r + u1r, O0i = u0i + u1i;
    float O2r = u0r - u1r, O2i = u0i - u1i;
    float O1r = v0r + v1i, O1i = v0i - v1r;
    float O3r = v0r - v1i, O3i = v0i + v1r;
    float t1r = RC2 * (O1r + O1i), t1i = RC2 * (O1i - O1r);
    float t2r = O2i,               t2i = -O2r;
    float t3r = RC2 * (O3i - O3r), t3i = -RC2 * (O3r + O3i);
    float xr[8], xi[8];
    xr[0] = E0r + O0r; xi[0] = E0i + O0i;
    xr[4] = E0r - O0r; xi[4] = E0i - O0i;
    xr[1] = E1r + t1r; xi[1] = E1i + t1i;
    xr[5] = E1r - t1r; xi[5] = E1i - t1i;
    xr[2] = E2r + t2r; xi[2] = E2i + t2i;
    xr[6] = E2r - t2r; xi[6] = E2i - t2i;
    xr[3] = E3r + t3r; xi[3] = E3i + t3i;
    xr[7] = E3r - t3r; xi[7] = E3i - t3i;
#pragma unroll
    for (int q = 0; q < 8; ++q) {
        int idx = base + q * L;
        int ph = idx + (idx >> 3);
        pr[ph] = xr[q];
        pi_[ph] = xi[q];
    }
}

// ---------------- fused row-FFT + bin+pack ----------------
// Blocks [0, ROWBLK): row FFTs. Blocks [ROWBLK, ROWBLK+256): bin + weight pack.
// Pack stores 12 fp16 weights (w0 UNSCALED, healthy fp16 range) + meta word.

#define LDSP 576
#define ROWBLK (BC * 64)
__global__ void __launch_bounds__(256) k_fft_row_bin(
    const float* __restrict__ x, float2* __restrict__ grid,
    const float* __restrict__ kt, unsigned* __restrict__ cnt,
    unsigned* __restrict__ meta, __half2* __restrict__ whalf) {
    __shared__ float re[4][LDSP], im[4][LDSP];
    int b = blockIdx.x;
    int t = threadIdx.x;
    if (b >= ROWBLK) {
        // ---- bin + pack ----
        int m = (b - ROWBLK) * 256 + t;
        float tmx = kt[m] * KSCALE;
        float tmy = kt[MM + m] * KSCALE;
        float bx = floorf(tmx), by = floorf(tmy);
        int ibx = (int)bx & (GSZ - 1);
        int iby = (int)by & (GSZ - 1);
        int tile = ((ibx >> 4) << 5) | (iby >> 4);
        unsigned slot = atomicAdd(&cnt[tile], 1u);
        if (slot < CAP) {
            int idx = tile * CAP + (int)slot;
            int lx = ibx & 15;
            int ly = iby & 15;
            meta[idx] = ((unsigned)m << 8) | (unsigned)(lx << 4) | (unsigned)ly;
            float w0[6], w1[6];
#pragma unroll
            for (int o = 0; o < 6; ++o) {
                float offv = (float)(o - 2);
                w0[o] = kb_weight(tmx - (bx + offv));
                w1[o] = kb_weight(tmy - (by + offv));
            }
            __half2* wp = whalf + (size_t)idx * 6;
            wp[0] = __half2(__float2half_rn(w0[0]), __float2half_rn(w0[1]));
            wp[1] = __half2(__float2half_rn(w0[2]), __float2half_rn(w0[3]));
            wp[2] = __half2(__float2half_rn(w0[4]), __float2half_rn(w0[5]));
            wp[3] = __half2(__float2half_rn(w1[0]), __float2half_rn(w1[1]));
            wp[4] = __half2(__float2half_rn(w1[2]), __float2half_rn(w1[3]));
            wp[5] = __half2(__float2half_rn(w1[4]), __float2half_rn(w1[5]));
        }
        return;
    }
    int w = t >> 6;
    int l = t & 63;
    int rg = (b & 63) * 4 + w;
    int bc = b >> 6;
    int r = (rg < 128) ? rg : rg + 256;
    int r_img = rg ^ 128;
    float scx = kb_ft_inv((float)(r_img - 128) * (1.0f / (float)GSZ));
    const float* xrow = x + ((size_t)bc * NN + (size_t)r_img) * NN;
#pragma unroll
    for (int e = 0; e < 8; ++e) {
        int i = e * 64 + l;
        float v = 0.0f;
        if (i < 128 || i >= 384) {
            int y = (i + 128) & (GSZ - 1);
            float scy = kb_ft_inv((float)(y - 128) * (1.0f / (float)GSZ));
            v = xrow[y] * scx * scy;
        }
        int rev = (l & 7) * 64 + (l >> 3) * 8 + e;
        int ph = rev + (rev >> 3);
        re[w][ph] = v;
        im[w][ph] = 0.0f;
    }
    __syncthreads();
    radix8_stage<1>(re[w], im[w], l);
    __syncthreads();
    radix8_stage<8>(re[w], im[w], l);
    __syncthreads();
    radix8_stage<64>(re[w], im[w], l);
    __syncthreads();
    size_t gbase = (size_t)bc * GG + (size_t)r * GSZ;
#pragma unroll
    for (int e = 0; e < 8; ++e) {
        int k = e * 64 + l;
        int ph = k + (k >> 3);
        grid[gbase + k] = make_float2(re[w][ph], im[w][ph]);
    }
}

// ---------------- column FFT (unchanged) ----------------

#define CSTR 577
__global__ void __launch_bounds__(256) k_fft_col(float2* __restrict__ grid) {
    __shared__ float re[16][CSTR], im[16][CSTR];
    int b = blockIdx.x;
    int bc = b >> 5;
    int c0 = (b & 31) << 4;
    size_t base = (size_t)bc * GG + (size_t)c0;
    int t = threadIdx.x;
#pragma unroll
    for (int it = 0; it < 32; ++it) {
        int idx = it * 256 + t;
        int row = idx >> 4, col = idx & 15;
        float2 v = make_float2(0.0f, 0.0f);
        if (row < 128 || row >= 384)
            v = grid[base + (size_t)row * GSZ + col];
        int rev = (row & 7) * 64 + ((row >> 3) & 7) * 8 + (row >> 6);
        int ph = rev + (rev >> 3);
        re[col][ph] = v.x;
        im[col][ph] = v.y;
    }
    __syncthreads();
    int col = t & 15, jg = t >> 4;
#pragma unroll
    for (int k = 0; k < 4; ++k) radix8_stage<1>(re[col], im[col], jg + 16 * k);
    __syncthreads();
#pragma unroll
    for (int k = 0; k < 4; ++k) radix8_stage<8>(re[col], im[col], jg + 16 * k);
    __syncthreads();
#pragma unroll
    for (int k = 0; k < 4; ++k) radix8_stage<64>(re[col], im[col], jg + 16 * k);
    __syncthreads();
    __half2* ghp = gh_plane(grid, bc);
#pragma unroll
    for (int it = 0; it < 32; ++it) {
        int idx = it * 256 + t;
        int row = idx >> 4, c = idx & 15;
        int ph = row + (row >> 3);
        ghp[(size_t)row * GSZ + c0 + c] = __float22half2_rn(
            make_float2(re[c][ph] * SSCALE, im[c][ph] * SSCALE));
    }
}

// ---------------- table-driven fp16 tile gather ----------------
// 4096 blocks x 128 threads, block = (tile, bc-quad). LDS = 4 planes (7.7 KB).
// Each lane owns point s: reads meta+whalf (coalesced, slot-indexed), converts
// 12 fp16 weights to fp32 (w0 * 2^-24, exact pow2), then 36 taps x 2 planes.

__global__ void __launch_bounds__(128, 6) k_gather_tile(
    const float2* __restrict__ grid, const unsigned* __restrict__ cnt,
    const unsigned* __restrict__ meta, const __half2* __restrict__ whalf,
    float2* __restrict__ out) {
    __shared__ __half2 ldsh[QPL * PLANE];   // 7728 B (total LDS)
    int bid = blockIdx.x;
    int b = ((bid & 7) << 9) | (bid >> 3);  // bijective XCD swizzle (4096 = 8*512)
    int tile = b >> 2;
    int quad = b & 3;
    int bc0 = quad * QPL;
    int tx0 = (tile >> 5) << 4;
    int ty0 = (tile & 31) << 4;
    int t = threadIdx.x;
#pragma unroll
    for (int k = 0; k < 14; ++k) {
        int idx = t + (k << 7);
        if (idx < NPQ) {
            int p = idx / (TRW * TRW);
            int rem = idx - p * (TRW * TRW);
            int r = rem / TRW;
            int c = rem - r * TRW;
            int row = (tx0 - 2 + r) & (GSZ - 1);
            int col = (ty0 - 2 + c) & (GSZ - 1);
            ldsh[p * PLANE + r * TPITCH + c] =
                gh_plane_c(grid, bc0 + p)[(size_t)row * GSZ + col];
        }
    }
    int n = (int)cnt[tile];
    if (n > CAP) n = CAP;
    __syncthreads();
    int g = t >> 6;                         // wave -> plane pair (2g, 2g+1)
    int baseA = (2 * g) * PLANE;
    int baseB = baseA + PLANE;
    int bcA = bc0 + 2 * g, bcB = bcA + 1;
    for (int s = (t & 63); s < n; s += 64) {
        int idx = tile * CAP + s;
        unsigned mc = meta[idx];
        int m = (int)(mc >> 8);
        int lx = (int)((mc >> 4) & 15u);
        int ly = (int)(mc & 15u);
        const __half2* wp = whalf + (size_t)idx * 6;
        __half2 p0 = wp[0], p1 = wp[1], p2 = wp[2];
        __half2 q0 = wp[3], q1 = wp[4], q2 = wp[5];
        float w0v[6], w1v[6];
        w0v[0] = __low2float(p0) * INV_SSCALE;
        w0v[1] = __high2float(p0) * INV_SSCALE;
        w0v[2] = __low2float(p1) * INV_SSCALE;
        w0v[3] = __high2float(p1) * INV_SSCALE;
        w0v[4] = __low2float(p2) * INV_SSCALE;
        w0v[5] = __high2float(p2) * INV_SSCALE;
        w1v[0] = __low2float(q0);
        w1v[1] = __high2float(q0);
        w1v[2] = __low2float(q1);
        w1v[3] = __high2float(q1);
        w1v[4] = __low2float(q2);
        w1v[5] = __high2float(q2);
        int off0 = lx * TPITCH + ly;
        float arA = 0.f, aiA = 0.f, arB = 0.f, aiB = 0.f;
#pragma unroll
        for (int ii = 0; ii < 6; ++ii) {
            float wi = w0v[ii];
            int rowoff = off0 + ii * TPITCH;
#pragma unroll
            for (int j = 0; j < 6; ++j) {
                float wv = wi * w1v[j];
                int o = rowoff + j;
                float2 vA = __half22float2(ldsh[baseA + o]);
                float2 vB = __half22float2(ldsh[baseB + o]);
                arA = fmaf(wv, vA.x, arA);
                aiA = fmaf(wv, vA.y, aiA);
                arB = fmaf(wv, vB.x, arB);
                aiB = fmaf(wv, vB.y, aiB);
            }
        }
        out[(size_t)bcA * MM + m] = make_float2(arA, aiA);
        out[(size_t)bcB * MM + m] = make_float2(arB, aiB);
    }
}

// Fallback gather (reads fp16 spectrum) if ws is too small for the tables.
__global__ void k_gather(const float2* __restrict__ grid, const float* __restrict__ kt,
                         float2* __restrict__ out) {
    int tid = blockIdx.x * blockDim.x + threadIdx.x;
    int m = tid & (MM - 1);
    int bc = tid >> 16;
    float tmx = kt[m] * KSCALE;
    float tmy = kt[MM + m] * KSCALE;
    float bx = floorf(tmx), by = floorf(tmy);
    int ibx = (int)bx, iby = (int)by;
    float w0[6], w1[6];
    int ix[6], iy[6];
#pragma unroll
    for (int o = 0; o < 6; ++o) {
        float offv = (float)(o - 2);
        w0[o] = kb_weight(tmx - (bx + offv)) * INV_SSCALE;
        w1[o] = kb_weight(tmy - (by + offv));
        ix[o] = (ibx + (o - 2) + GSZ) & (GSZ - 1);
        iy[o] = (iby + (o - 2) + GSZ) & (GSZ - 1);
    }
    const __half2* img = gh_plane_c(grid, bc);
    float ar = 0.0f, ai = 0.0f;
#pragma unroll
    for (int i = 0; i < 6; ++i) {
        const __half2* rowp = img + (size_t)ix[i] * GSZ;
        float wi = w0[i];
#pragma unroll
        for (int j = 0; j < 6; ++j) {
            float2 v = __half22float2(rowp[iy[j]]);
            float wv = wi * w1[j];
            ar = fmaf(wv, v.x, ar);
            ai = fmaf(wv, v.y, ai);
        }
    }
    out[(size_t)bc * MM + m] = make_float2(ar, ai);
}

// Standalone row FFT for the fallback path (no binning).
__global__ void __launch_bounds__(256) k_fft_row(const float* __restrict__ x,
                                                 float2* __restrict__ grid) {
    __shared__ float re[4][LDSP], im[4][LDSP];
    int b = blockIdx.x;
    int t = threadIdx.x;
    int w = t >> 6;
    int l = t & 63;
    int rg = (b & 63) * 4 + w;
    int bc = b >> 6;
    int r = (rg < 128) ? rg : rg + 256;
    int r_img = rg ^ 128;
    float scx = kb_ft_inv((float)(r_img - 128) * (1.0f / (float)GSZ));
    const float* xrow = x + ((size_t)bc * NN + (size_t)r_img) * NN;
#pragma unroll
    for (int e = 0; e < 8; ++e) {
        int i = e * 64 + l;
        float v = 0.0f;
        if (i < 128 || i >= 384) {
            int y = (i + 128) & (GSZ - 1);
            float scy = kb_ft_inv((float)(y - 128) * (1.0f / (float)GSZ));
            v = xrow[y] * scx * scy;
        }
        int rev = (l & 7) * 64 + (l >> 3) * 8 + e;
        int ph = rev + (rev >> 3);
        re[w][ph] = v;
        im[w][ph] = 0.0f;
    }
    __syncthreads();
    radix8_stage<1>(re[w], im[w], l);
    __syncthreads();
    radix8_stage<8>(re[w], im[w], l);
    __syncthreads();
    radix8_stage<64>(re[w], im[w], l);
    __syncthreads();
    size_t gbase = (size_t)bc * GG + (size_t)r * GSZ;
#pragma unroll
    for (int e = 0; e < 8; ++e) {
        int k = e * 64 + l;
        int ph = k + (k >> 3);
        grid[gbase + k] = make_float2(re[w][ph], im[w][ph]);
    }
}

// ---------------- launch ----------------

extern "C" void kernel_launch(void* const* d_in, const int* in_sizes, int n_in,
                              void* d_out, int out_size, void* d_ws, size_t ws_size,
                              hipStream_t stream) {
    const float* x = (const float*)d_in[0];
    const float* kt = (const float*)d_in[1];
    float2* out = (float2*)d_out;
    char* ws = (char*)d_ws;

    const size_t GRID_BYTES = (size_t)BC * GG * sizeof(float2);      // 33,554,432
    const size_t CNT_BYTES = 1024 * sizeof(unsigned);                // 4,096
    const size_t META_BYTES = (size_t)1024 * CAP * sizeof(unsigned); // 589,824
    const size_t WH_BYTES = (size_t)1024 * CAP * 6 * sizeof(__half2);// 3,538,944
    float2* grid = (float2*)ws;
    unsigned* cnt = (unsigned*)(ws + GRID_BYTES);
    unsigned* meta = (unsigned*)(ws + GRID_BYTES + CNT_BYTES);
    __half2* whalf = (__half2*)(ws + GRID_BYTES + CNT_BYTES + META_BYTES);
    const size_t NEED = GRID_BYTES + CNT_BYTES + META_BYTES + WH_BYTES; // 37,687,296

    if (ws_size >= NEED) {
        hipMemsetAsync(cnt, 0, CNT_BYTES, stream);
        k_fft_row_bin<<<ROWBLK + 256, 256, 0, stream>>>(x, grid, kt, cnt, meta, whalf);
        k_fft_col<<<BC * (GSZ / 16), 256, 0, stream>>>(grid);
        k_gather_tile<<<4096, 128, 0, stream>>>(grid, cnt, meta, whalf, out);
    } else {
        k_fft_row<<<BC * 64, 256, 0, stream>>>(x, grid);
        k_fft_col<<<BC * (GSZ / 16), 256, 0, stream>>>(grid);
        k_gather<<<(BC * MM) / 256, 256, 0, stream>>>(grid, kt, out);
    }
}

// Round 15
// 67.505 us; speedup vs baseline: 1.1480x; 1.0021x over previous
//
#include <hip/hip_runtime.h>
#include <hip/hip_fp16.h>
#include <math.h>

// Problem constants (match reference)
#define NN 256
#define GSZ 512
#define GG (GSZ * GSZ)
#define BC 16            // B*C
#define MM 65536
#define ALPHA_C 14.04f   // 2.34 * W
#define WKER 6
#define PI_F 3.14159265358979f
#define RC2 0.70710678118654752f
#define KSCALE 81.48733086305042f  // GSZ / (2*pi)

// fp16 spectrum scaling (r10): pack Xk*2^24; 2^-24 applied to w0 at use (exact).
#define SSCALE 16777216.0f                 // 2^24
#define INV_SSCALE 5.9604644775390625e-8f  // 2^-24 (exact)

// Gather tiling: 16x16 cells, 1024 tiles, ~64 pts/tile
#define CAP 144          // bucket capacity (mean 64, sd 8 -> +10 sigma)
#define TRW 21           // stencil region rows/cols per tile (16 + 5)
#define TPITCH 23        // LDS row pitch in half2 (odd -> all 32 banks)
#define PLANE (TRW * TPITCH)     // 483 half2 per bc plane
#define QPL 8            // planes (bc images) per gather block
#define NPQ (QPL * TRW * TRW)    // 3528 half2 staged per block

// fp16 spectrum plane: lives in rows [128,384) of each fp32 grid plane.
__device__ __forceinline__ __half2* gh_plane(float2* grid, int bc) {
    return (__half2*)((char*)grid + (size_t)bc * (GG * 8) + 524288);
}
__device__ __forceinline__ const __half2* gh_plane_c(const float2* grid, int bc) {
    return (const __half2*)((const char*)grid + (size_t)bc * (GG * 8) + 524288);
}

// ---------------- device math helpers ----------------

__device__ __forceinline__ float bessel_i0(float x) {
    if (x < 3.75f) {
        float t = x * (1.0f / 3.75f);
        float t2 = t * t;
        return 1.0f + t2 * (3.5156229f + t2 * (3.0899424f + t2 * (1.2067492f +
                     t2 * (0.2659732f + t2 * (0.0360768f + t2 * 0.0045813f)))));
    } else {
        float t = 3.75f / x;
        float p = 0.39894228f + t * (0.01328592f + t * (0.00225319f + t * (-0.00157565f +
                  t * (0.00916281f + t * (-0.02057706f + t * (0.02635537f +
                  t * (-0.01647633f + t * 0.00392377f)))))));
        return p * __expf(x) * rsqrtf(x);
    }
}

__device__ __forceinline__ float kb_weight(float d) {
    float r = d * (2.0f / (float)WKER);
    float u = 1.0f - r * r;
    if (u <= 0.0f) return 0.0f;
    return bessel_i0(ALPHA_C * sqrtf(u)) * (1.0f / (float)WKER);
}

__device__ __forceinline__ float kb_ft_inv(float t) {
    float a = PI_F * (float)WKER * t;
    float s2 = ALPHA_C * ALPHA_C - a * a;
    float z = sqrtf(fabsf(s2)) + 1e-12f;
    float sh = 0.5f * (__expf(z) - __expf(-z));
    return z / sh;
}

__device__ __forceinline__ void cmul(float& zr, float& zi, float wr, float wi) {
    float r = zr * wr - zi * wi;
    zi = zr * wi + zi * wr;
    zr = r;
}

// ---------------- radix-8 stage (unchanged) ----------

template <int L>
__device__ __forceinline__ void radix8_stage(float* pr, float* pi_, int j) {
    int pos = j & (L - 1);
    int base = (j - pos) * 8 + pos;
    float ar[8], ai[8];
#pragma unroll
    for (int r = 0; r < 8; ++r) {
        int idx = base + r * L;
        int ph = idx + (idx >> 3);
        ar[r] = pr[ph];
        ai[r] = pi_[ph];
    }
    if (L > 1) {
        float th = (float)pos * (-PI_F / (4.0f * (float)L));
        float s1, c1;
        __sincosf(th, &s1, &c1);
        float wr = c1, wi = s1;
#pragma unroll
        for (int r = 1; r < 8; ++r) {
            cmul(ar[r], ai[r], wr, wi);
            float nr = wr * c1 - wi * s1;
            wi = wr * s1 + wi * c1;
            wr = nr;
        }
    }
    float s0r = ar[0] + ar[4], s0i = ai[0] + ai[4];
    float d0r = ar[0] - ar[4], d0i = ai[0] - ai[4];
    float s1r = ar[2] + ar[6], s1i = ai[2] + ai[6];
    float d1r = ar[2] - ar[6], d1i = ai[2] - ai[6];
    float E0r = s0r + s1r, E0i = s0i + s1i;
    float E2r = s0r - s1r, E2i = s0i - s1i;
    float E1r = d0r + d1i, E1i = d0i - d1r;
    float E3r = d0r - d1i, E3i = d0i + d1r;
    float u0r = ar[1] + ar[5], u0i = ai[1] + ai[5];
    float v0r = ar[1] - ar[5], v0i = ai[1] - ai[5];
    float u1r = ar[3] + ar[7], u1i = ai[3] + ai[7];
    float v1r = ar[3] - ar[7], v1i = ai[3] - ai[7];
    float O0r = u0r + u1r, O0i = u0i + u1i;
    float O2r = u0r - u1r, O2i = u0i - u1i;
    float O1r = v0r + v1i, O1i = v0i - v1r;
    float O3r = v0r - v1i, O3i = v0i + v1r;
    float t1r = RC2 * (O1r + O1i), t1i = RC2 * (O1i - O1r);
    float t2r = O2i,               t2i = -O2r;
    float t3r = RC2 * (O3i - O3r), t3i = -RC2 * (O3r + O3i);
    float xr[8], xi[8];
    xr[0] = E0r + O0r; xi[0] = E0i + O0i;
    xr[4] = E0r - O0r; xi[4] = E0i - O0i;
    xr[1] = E1r + t1r; xi[1] = E1i + t1i;
    xr[5] = E1r - t1r; xi[5] = E1i - t1i;
    xr[2] = E2r + t2r; xi[2] = E2i + t2i;
    xr[6] = E2r - t2r; xi[6] = E2i - t2i;
    xr[3] = E3r + t3r; xi[3] = E3i + t3i;
    xr[7] = E3r - t3r; xi[7] = E3i - t3i;
#pragma unroll
    for (int q = 0; q < 8; ++q) {
        int idx = base + q * L;
        int ph = idx + (idx >> 3);
        pr[ph] = xr[q];
        pi_[ph] = xi[q];
    }
}

// ---------------- fused row-FFT + bin+pack (unchanged from round 14) --------

#define LDSP 576
#define ROWBLK (BC * 64)
__global__ void __launch_bounds__(256) k_fft_row_bin(
    const float* __restrict__ x, float2* __restrict__ grid,
    const float* __restrict__ kt, unsigned* __restrict__ cnt,
    unsigned* __restrict__ meta, __half2* __restrict__ whalf) {
    __shared__ float re[4][LDSP], im[4][LDSP];
    int b = blockIdx.x;
    int t = threadIdx.x;
    if (b >= ROWBLK) {
        int m = (b - ROWBLK) * 256 + t;
        float tmx = kt[m] * KSCALE;
        float tmy = kt[MM + m] * KSCALE;
        float bx = floorf(tmx), by = floorf(tmy);
        int ibx = (int)bx & (GSZ - 1);
        int iby = (int)by & (GSZ - 1);
        int tile = ((ibx >> 4) << 5) | (iby >> 4);
        unsigned slot = atomicAdd(&cnt[tile], 1u);
        if (slot < CAP) {
            int idx = tile * CAP + (int)slot;
            int lx = ibx & 15;
            int ly = iby & 15;
            meta[idx] = ((unsigned)m << 8) | (unsigned)(lx << 4) | (unsigned)ly;
            float w0[6], w1[6];
#pragma unroll
            for (int o = 0; o < 6; ++o) {
                float offv = (float)(o - 2);
                w0[o] = kb_weight(tmx - (bx + offv));
                w1[o] = kb_weight(tmy - (by + offv));
            }
            __half2* wp = whalf + (size_t)idx * 6;
            wp[0] = __half2(__float2half_rn(w0[0]), __float2half_rn(w0[1]));
            wp[1] = __half2(__float2half_rn(w0[2]), __float2half_rn(w0[3]));
            wp[2] = __half2(__float2half_rn(w0[4]), __float2half_rn(w0[5]));
            wp[3] = __half2(__float2half_rn(w1[0]), __float2half_rn(w1[1]));
            wp[4] = __half2(__float2half_rn(w1[2]), __float2half_rn(w1[3]));
            wp[5] = __half2(__float2half_rn(w1[4]), __float2half_rn(w1[5]));
        }
        return;
    }
    int w = t >> 6;
    int l = t & 63;
    int rg = (b & 63) * 4 + w;
    int bc = b >> 6;
    int r = (rg < 128) ? rg : rg + 256;
    int r_img = rg ^ 128;
    float scx = kb_ft_inv((float)(r_img - 128) * (1.0f / (float)GSZ));
    const float* xrow = x + ((size_t)bc * NN + (size_t)r_img) * NN;
#pragma unroll
    for (int e = 0; e < 8; ++e) {
        int i = e * 64 + l;
        float v = 0.0f;
        if (i < 128 || i >= 384) {
            int y = (i + 128) & (GSZ - 1);
            float scy = kb_ft_inv((float)(y - 128) * (1.0f / (float)GSZ));
            v = xrow[y] * scx * scy;
        }
        int rev = (l & 7) * 64 + (l >> 3) * 8 + e;
        int ph = rev + (rev >> 3);
        re[w][ph] = v;
        im[w][ph] = 0.0f;
    }
    __syncthreads();
    radix8_stage<1>(re[w], im[w], l);
    __syncthreads();
    radix8_stage<8>(re[w], im[w], l);
    __syncthreads();
    radix8_stage<64>(re[w], im[w], l);
    __syncthreads();
    size_t gbase = (size_t)bc * GG + (size_t)r * GSZ;
#pragma unroll
    for (int e = 0; e < 8; ++e) {
        int k = e * 64 + l;
        int ph = k + (k >> 3);
        grid[gbase + k] = make_float2(re[w][ph], im[w][ph]);
    }
}

// ---------------- column FFT: 512 threads (16 waves/CU at 2 blocks/CU) ------

#define CSTR 577
__global__ void __launch_bounds__(512) k_fft_col(float2* __restrict__ grid) {
    __shared__ float re[16][CSTR], im[16][CSTR];
    int b = blockIdx.x;
    int bc = b >> 5;
    int c0 = (b & 31) << 4;
    size_t base = (size_t)bc * GG + (size_t)c0;
    int t = threadIdx.x;
#pragma unroll
    for (int it = 0; it < 16; ++it) {
        int idx = it * 512 + t;
        int row = idx >> 4, col = idx & 15;
        float2 v = make_float2(0.0f, 0.0f);
        if (row < 128 || row >= 384)
            v = grid[base + (size_t)row * GSZ + col];
        int rev = (row & 7) * 64 + ((row >> 3) & 7) * 8 + (row >> 6);
        int ph = rev + (rev >> 3);
        re[col][ph] = v.x;
        im[col][ph] = v.y;
    }
    __syncthreads();
    int col = t & 15, jg = t >> 4;   // jg in [0,32): 2 butterflies per thread
#pragma unroll
    for (int k = 0; k < 2; ++k) radix8_stage<1>(re[col], im[col], jg + 32 * k);
    __syncthreads();
#pragma unroll
    for (int k = 0; k < 2; ++k) radix8_stage<8>(re[col], im[col], jg + 32 * k);
    __syncthreads();
#pragma unroll
    for (int k = 0; k < 2; ++k) radix8_stage<64>(re[col], im[col], jg + 32 * k);
    __syncthreads();
    __half2* ghp = gh_plane(grid, bc);
#pragma unroll
    for (int it = 0; it < 16; ++it) {
        int idx = it * 512 + t;
        int row = idx >> 4, c = idx & 15;
        int ph = row + (row >> 3);
        ghp[(size_t)row * GSZ + c0 + c] = __float22half2_rn(
            make_float2(re[c][ph] * SSCALE, im[c][ph] * SSCALE));
    }
}

// ---------------- table-driven fp16 oct gather ----------------
// 2048 blocks x 128 threads, block = (tile, bc-oct). LDS = 8 planes (15.5 KB)
// -> 10 blocks/CU (20 waves). Wave g handles planes 4g..4g+3; lanes stripe
// points; weights read from the precomputed table (4 visits/point total).

__global__ void __launch_bounds__(128, 6) k_gather_tile(
    const float2* __restrict__ grid, const unsigned* __restrict__ cnt,
    const unsigned* __restrict__ meta, const __half2* __restrict__ whalf,
    float2* __restrict__ out) {
    __shared__ __half2 ldsh[QPL * PLANE];   // 15456 B (total LDS)
    int bid = blockIdx.x;
    int b = ((bid & 7) << 8) | (bid >> 3);  // bijective XCD swizzle (2048 = 8*256)
    int tile = b >> 1;
    int oct = b & 1;
    int bc0 = oct * QPL;
    int tx0 = (tile >> 5) << 4;
    int ty0 = (tile & 31) << 4;
    int t = threadIdx.x;
#pragma unroll
    for (int k = 0; k < 28; ++k) {
        int idx = t + (k << 7);
        if (idx < NPQ) {
            int p = idx / (TRW * TRW);
            int rem = idx - p * (TRW * TRW);
            int r = rem / TRW;
            int c = rem - r * TRW;
            int row = (tx0 - 2 + r) & (GSZ - 1);
            int col = (ty0 - 2 + c) & (GSZ - 1);
            ldsh[p * PLANE + r * TPITCH + c] =
                gh_plane_c(grid, bc0 + p)[(size_t)row * GSZ + col];
        }
    }
    int n = (int)cnt[tile];
    if (n > CAP) n = CAP;
    __syncthreads();
    int g = t >> 6;                         // wave -> planes 4g..4g+3
    int base0 = (4 * g) * PLANE;
    int base1 = base0 + PLANE;
    int base2 = base1 + PLANE;
    int base3 = base2 + PLANE;
    int bcw = bc0 + 4 * g;
    for (int s = (t & 63); s < n; s += 64) {
        int idx = tile * CAP + s;
        unsigned mc = meta[idx];
        int m = (int)(mc >> 8);
        int lx = (int)((mc >> 4) & 15u);
        int ly = (int)(mc & 15u);
        const __half2* wp = whalf + (size_t)idx * 6;
        __half2 p0 = wp[0], p1 = wp[1], p2 = wp[2];
        __half2 q0 = wp[3], q1 = wp[4], q2 = wp[5];
        float w0v[6], w1v[6];
        w0v[0] = __low2float(p0) * INV_SSCALE;
        w0v[1] = __high2float(p0) * INV_SSCALE;
        w0v[2] = __low2float(p1) * INV_SSCALE;
        w0v[3] = __high2float(p1) * INV_SSCALE;
        w0v[4] = __low2float(p2) * INV_SSCALE;
        w0v[5] = __high2float(p2) * INV_SSCALE;
        w1v[0] = __low2float(q0);
        w1v[1] = __high2float(q0);
        w1v[2] = __low2float(q1);
        w1v[3] = __high2float(q1);
        w1v[4] = __low2float(q2);
        w1v[5] = __high2float(q2);
        int off0 = lx * TPITCH + ly;
        float ar0 = 0.f, ai0 = 0.f, ar1 = 0.f, ai1 = 0.f;
        float ar2 = 0.f, ai2 = 0.f, ar3 = 0.f, ai3 = 0.f;
#pragma unroll
        for (int ii = 0; ii < 6; ++ii) {
            float wi = w0v[ii];
            int rowoff = off0 + ii * TPITCH;
#pragma unroll
            for (int j = 0; j < 6; ++j) {
                float wv = wi * w1v[j];
                int o = rowoff + j;
                float2 v0 = __half22float2(ldsh[base0 + o]);
                float2 v1 = __half22float2(ldsh[base1 + o]);
                float2 v2 = __half22float2(ldsh[base2 + o]);
                float2 v3 = __half22float2(ldsh[base3 + o]);
                ar0 = fmaf(wv, v0.x, ar0);
                ai0 = fmaf(wv, v0.y, ai0);
                ar1 = fmaf(wv, v1.x, ar1);
                ai1 = fmaf(wv, v1.y, ai1);
                ar2 = fmaf(wv, v2.x, ar2);
                ai2 = fmaf(wv, v2.y, ai2);
                ar3 = fmaf(wv, v3.x, ar3);
                ai3 = fmaf(wv, v3.y, ai3);
            }
        }
        out[(size_t)(bcw + 0) * MM + m] = make_float2(ar0, ai0);
        out[(size_t)(bcw + 1) * MM + m] = make_float2(ar1, ai1);
        out[(size_t)(bcw + 2) * MM + m] = make_float2(ar2, ai2);
        out[(size_t)(bcw + 3) * MM + m] = make_float2(ar3, ai3);
    }
}

// Fallback gather (reads fp16 spectrum) if ws is too small for the tables.
__global__ void k_gather(const float2* __restrict__ grid, const float* __restrict__ kt,
                         float2* __restrict__ out) {
    int tid = blockIdx.x * blockDim.x + threadIdx.x;
    int m = tid & (MM - 1);
    int bc = tid >> 16;
    float tmx = kt[m] * KSCALE;
    float tmy = kt[MM + m] * KSCALE;
    float bx = floorf(tmx), by = floorf(tmy);
    int ibx = (int)bx, iby = (int)by;
    float w0[6], w1[6];
    int ix[6], iy[6];
#pragma unroll
    for (int o = 0; o < 6; ++o) {
        float offv = (float)(o - 2);
        w0[o] = kb_weight(tmx - (bx + offv)) * INV_SSCALE;
        w1[o] = kb_weight(tmy - (by + offv));
        ix[o] = (ibx + (o - 2) + GSZ) & (GSZ - 1);
        iy[o] = (iby + (o - 2) + GSZ) & (GSZ - 1);
    }
    const __half2* img = gh_plane_c(grid, bc);
    float ar = 0.0f, ai = 0.0f;
#pragma unroll
    for (int i = 0; i < 6; ++i) {
        const __half2* rowp = img + (size_t)ix[i] * GSZ;
        float wi = w0[i];
#pragma unroll
        for (int j = 0; j < 6; ++j) {
            float2 v = __half22float2(rowp[iy[j]]);
            float wv = wi * w1[j];
            ar = fmaf(wv, v.x, ar);
            ai = fmaf(wv, v.y, ai);
        }
    }
    out[(size_t)bc * MM + m] = make_float2(ar, ai);
}

// Standalone row FFT for the fallback path (no binning).
__global__ void __launch_bounds__(256) k_fft_row(const float* __restrict__ x,
                                                 float2* __restrict__ grid) {
    __shared__ float re[4][LDSP], im[4][LDSP];
    int b = blockIdx.x;
    int t = threadIdx.x;
    int w = t >> 6;
    int l = t & 63;
    int rg = (b & 63) * 4 + w;
    int bc = b >> 6;
    int r = (rg < 128) ? rg : rg + 256;
    int r_img = rg ^ 128;
    float scx = kb_ft_inv((float)(r_img - 128) * (1.0f / (float)GSZ));
    const float* xrow = x + ((size_t)bc * NN + (size_t)r_img) * NN;
#pragma unroll
    for (int e = 0; e < 8; ++e) {
        int i = e * 64 + l;
        float v = 0.0f;
        if (i < 128 || i >= 384) {
            int y = (i + 128) & (GSZ - 1);
            float scy = kb_ft_inv((float)(y - 128) * (1.0f / (float)GSZ));
            v = xrow[y] * scx * scy;
        }
        int rev = (l & 7) * 64 + (l >> 3) * 8 + e;
        int ph = rev + (rev >> 3);
        re[w][ph] = v;
        im[w][ph] = 0.0f;
    }
    __syncthreads();
    radix8_stage<1>(re[w], im[w], l);
    __syncthreads();
    radix8_stage<8>(re[w], im[w], l);
    __syncthreads();
    radix8_stage<64>(re[w], im[w], l);
    __syncthreads();
    size_t gbase = (size_t)bc * GG + (size_t)r * GSZ;
#pragma unroll
    for (int e = 0; e < 8; ++e) {
        int k = e * 64 + l;
        int ph = k + (k >> 3);
        grid[gbase + k] = make_float2(re[w][ph], im[w][ph]);
    }
}

// ---------------- launch ----------------

extern "C" void kernel_launch(void* const* d_in, const int* in_sizes, int n_in,
                              void* d_out, int out_size, void* d_ws, size_t ws_size,
                              hipStream_t stream) {
    const float* x = (const float*)d_in[0];
    const float* kt = (const float*)d_in[1];
    float2* out = (float2*)d_out;
    char* ws = (char*)d_ws;

    const size_t GRID_BYTES = (size_t)BC * GG * sizeof(float2);      // 33,554,432
    const size_t CNT_BYTES = 1024 * sizeof(unsigned);                // 4,096
    const size_t META_BYTES = (size_t)1024 * CAP * sizeof(unsigned); // 589,824
    const size_t WH_BYTES = (size_t)1024 * CAP * 6 * sizeof(__half2);// 3,538,944
    float2* grid = (float2*)ws;
    unsigned* cnt = (unsigned*)(ws + GRID_BYTES);
    unsigned* meta = (unsigned*)(ws + GRID_BYTES + CNT_BYTES);
    __half2* whalf = (__half2*)(ws + GRID_BYTES + CNT_BYTES + META_BYTES);
    const size_t NEED = GRID_BYTES + CNT_BYTES + META_BYTES + WH_BYTES; // 37,687,296

    if (ws_size >= NEED) {
        hipMemsetAsync(cnt, 0, CNT_BYTES, stream);
        k_fft_row_bin<<<ROWBLK + 256, 256, 0, stream>>>(x, grid, kt, cnt, meta, whalf);
        k_fft_col<<<BC * (GSZ / 16), 512, 0, stream>>>(grid);
        k_gather_tile<<<2048, 128, 0, stream>>>(grid, cnt, meta, whalf, out);
    } else {
        k_fft_row<<<BC * 64, 256, 0, stream>>>(x, grid);
        k_fft_col<<<BC * (GSZ / 16), 512, 0, stream>>>(grid);
        k_gather<<<(BC * MM) / 256, 256, 0, stream>>>(grid, kt, out);
    }
}

// Round 16
// 66.293 us; speedup vs baseline: 1.1690x; 1.0183x over previous
//
#include <hip/hip_runtime.h>
#include <hip/hip_fp16.h>
#include <math.h>

// Problem constants (match reference)
#define NN 256
#define GSZ 512
#define GG (GSZ * GSZ)
#define BC 16            // B*C
#define MM 65536
#define ALPHA_C 14.04f   // 2.34 * W
#define WKER 6
#define PI_F 3.14159265358979f
#define RC2 0.70710678118654752f
#define KSCALE 81.48733086305042f  // GSZ / (2*pi)

// fp16 scaling (r10): all fp16 data carries a 2^24 factor; 2^-24 folded into w0
// at use (exact pow2).
#define SSCALE 16777216.0f                 // 2^24
#define INV_SSCALE 5.9604644775390625e-8f  // 2^-24 (exact)

// Gather tiling: 16x16 cells, 1024 tiles, ~64 pts/tile
#define CAP 144          // bucket capacity (mean 64, sd 8 -> +10 sigma)
#define TRW 21           // stencil region rows/cols per tile (16 + 5)
#define TPITCH 23        // LDS row pitch in half2 (odd -> all 32 banks)
#define PLANE (TRW * TPITCH)     // 483 half2 per bc plane
#define QPL 8            // planes (bc images) per gather block
#define NPQ (QPL * TRW * TRW)    // 3528 half2 staged per block

// Per-bc plane layout inside the 2MB fp32-plane-sized slot:
//   region A [0, 0.5MB): row-FFT fp16 output, 256 rows x 512 cols half2
//   region B [0.5MB, 1.5MB): fp16 spectrum, 512 x 512 half2 (gather reads this)
__device__ __forceinline__ __half2* regA(float2* grid, int bc) {
    return (__half2*)((char*)grid + (size_t)bc * ((size_t)GG * 8));
}
__device__ __forceinline__ const __half2* regA_c(const float2* grid, int bc) {
    return (const __half2*)((const char*)grid + (size_t)bc * ((size_t)GG * 8));
}
__device__ __forceinline__ __half2* gh_plane(float2* grid, int bc) {
    return (__half2*)((char*)grid + (size_t)bc * ((size_t)GG * 8) + 524288);
}
__device__ __forceinline__ const __half2* gh_plane_c(const float2* grid, int bc) {
    return (const __half2*)((const char*)grid + (size_t)bc * ((size_t)GG * 8) + 524288);
}

// ---------------- device math helpers ----------------

__device__ __forceinline__ float bessel_i0(float x) {
    if (x < 3.75f) {
        float t = x * (1.0f / 3.75f);
        float t2 = t * t;
        return 1.0f + t2 * (3.5156229f + t2 * (3.0899424f + t2 * (1.2067492f +
                     t2 * (0.2659732f + t2 * (0.0360768f + t2 * 0.0045813f)))));
    } else {
        float t = 3.75f / x;
        float p = 0.39894228f + t * (0.01328592f + t * (0.00225319f + t * (-0.00157565f +
                  t * (0.00916281f + t * (-0.02057706f + t * (0.02635537f +
                  t * (-0.01647633f + t * 0.00392377f)))))));
        return p * __expf(x) * rsqrtf(x);
    }
}

__device__ __forceinline__ float kb_weight(float d) {
    float r = d * (2.0f / (float)WKER);
    float u = 1.0f - r * r;
    if (u <= 0.0f) return 0.0f;
    return bessel_i0(ALPHA_C * sqrtf(u)) * (1.0f / (float)WKER);
}

__device__ __forceinline__ float kb_ft_inv(float t) {
    float a = PI_F * (float)WKER * t;
    float s2 = ALPHA_C * ALPHA_C - a * a;
    float z = sqrtf(fabsf(s2)) + 1e-12f;
    float sh = 0.5f * (__expf(z) - __expf(-z));
    return z / sh;
}

__device__ __forceinline__ void cmul(float& zr, float& zi, float wr, float wi) {
    float r = zr * wr - zi * wi;
    zi = zr * wi + zi * wr;
    zr = r;
}

// ---------------- radix-8 stage (unchanged) ----------

template <int L>
__device__ __forceinline__ void radix8_stage(float* pr, float* pi_, int j) {
    int pos = j & (L - 1);
    int base = (j - pos) * 8 + pos;
    float ar[8], ai[8];
#pragma unroll
    for (int r = 0; r < 8; ++r) {
        int idx = base + r * L;
        int ph = idx + (idx >> 3);
        ar[r] = pr[ph];
        ai[r] = pi_[ph];
    }
    if (L > 1) {
        float th = (float)pos * (-PI_F / (4.0f * (float)L));
        float s1, c1;
        __sincosf(th, &s1, &c1);
        float wr = c1, wi = s1;
#pragma unroll
        for (int r = 1; r < 8; ++r) {
            cmul(ar[r], ai[r], wr, wi);
            float nr = wr * c1 - wi * s1;
            wi = wr * s1 + wi * c1;
            wr = nr;
        }
    }
    float s0r = ar[0] + ar[4], s0i = ai[0] + ai[4];
    float d0r = ar[0] - ar[4], d0i = ai[0] - ai[4];
    float s1r = ar[2] + ar[6], s1i = ai[2] + ai[6];
    float d1r = ar[2] - ar[6], d1i = ai[2] - ai[6];
    float E0r = s0r + s1r, E0i = s0i + s1i;
    float E2r = s0r - s1r, E2i = s0i - s1i;
    float E1r = d0r + d1i, E1i = d0i - d1r;
    float E3r = d0r - d1i, E3i = d0i + d1r;
    float u0r = ar[1] + ar[5], u0i = ai[1] + ai[5];
    float v0r = ar[1] - ar[5], v0i = ai[1] - ai[5];
    float u1r = ar[3] + ar[7], u1i = ai[3] + ai[7];
    float v1r = ar[3] - ar[7], v1i = ai[3] - ai[7];
    float O0r = u0r + u1r, O0i = u0i + u1i;
    float O2r = u0r - u1r, O2i = u0i - u1i;
    float O1r = v0r + v1i, O1i = v0i - v1r;
    float O3r = v0r - v1i, O3i = v0i + v1r;
    float t1r = RC2 * (O1r + O1i), t1i = RC2 * (O1i - O1r);
    float t2r = O2i,               t2i = -O2r;
    float t3r = RC2 * (O3i - O3r), t3i = -RC2 * (O3r + O3i);
    float xr[8], xi[8];
    xr[0] = E0r + O0r; xi[0] = E0i + O0i;
    xr[4] = E0r - O0r; xi[4] = E0i - O0i;
    xr[1] = E1r + t1r; xi[1] = E1i + t1i;
    xr[5] = E1r - t1r; xi[5] = E1i - t1i;
    xr[2] = E2r + t2r; xi[2] = E2i + t2i;
    xr[6] = E2r - t2r; xi[6] = E2i - t2i;
    xr[3] = E3r + t3r; xi[3] = E3i + t3i;
    xr[7] = E3r - t3r; xi[7] = E3i - t3i;
#pragma unroll
    for (int q = 0; q < 8; ++q) {
        int idx = base + q * L;
        int ph = idx + (idx >> 3);
        pr[ph] = xr[q];
        pi_[ph] = xi[q];
    }
}

// ---------------- fused row-FFT + bin+pack; fp16 output to region A ---------

#define LDSP 576
#define ROWBLK (BC * 64)
__global__ void __launch_bounds__(256) k_fft_row_bin(
    const float* __restrict__ x, float2* __restrict__ grid,
    const float* __restrict__ kt, unsigned* __restrict__ cnt,
    unsigned* __restrict__ meta, __half2* __restrict__ whalf) {
    __shared__ float re[4][LDSP], im[4][LDSP];
    int b = blockIdx.x;
    int t = threadIdx.x;
    if (b >= ROWBLK) {
        int m = (b - ROWBLK) * 256 + t;
        float tmx = kt[m] * KSCALE;
        float tmy = kt[MM + m] * KSCALE;
        float bx = floorf(tmx), by = floorf(tmy);
        int ibx = (int)bx & (GSZ - 1);
        int iby = (int)by & (GSZ - 1);
        int tile = ((ibx >> 4) << 5) | (iby >> 4);
        unsigned slot = atomicAdd(&cnt[tile], 1u);
        if (slot < CAP) {
            int idx = tile * CAP + (int)slot;
            int lx = ibx & 15;
            int ly = iby & 15;
            meta[idx] = ((unsigned)m << 8) | (unsigned)(lx << 4) | (unsigned)ly;
            float w0[6], w1[6];
#pragma unroll
            for (int o = 0; o < 6; ++o) {
                float offv = (float)(o - 2);
                w0[o] = kb_weight(tmx - (bx + offv));
                w1[o] = kb_weight(tmy - (by + offv));
            }
            __half2* wp = whalf + (size_t)idx * 6;
            wp[0] = __half2(__float2half_rn(w0[0]), __float2half_rn(w0[1]));
            wp[1] = __half2(__float2half_rn(w0[2]), __float2half_rn(w0[3]));
            wp[2] = __half2(__float2half_rn(w0[4]), __float2half_rn(w0[5]));
            wp[3] = __half2(__float2half_rn(w1[0]), __float2half_rn(w1[1]));
            wp[4] = __half2(__float2half_rn(w1[2]), __float2half_rn(w1[3]));
            wp[5] = __half2(__float2half_rn(w1[4]), __float2half_rn(w1[5]));
        }
        return;
    }
    int w = t >> 6;
    int l = t & 63;
    int rg = (b & 63) * 4 + w;
    int bc = b >> 6;
    int r = (rg < 128) ? rg : rg + 256;
    int r_img = rg ^ 128;
    float scx = kb_ft_inv((float)(r_img - 128) * (1.0f / (float)GSZ));
    const float* xrow = x + ((size_t)bc * NN + (size_t)r_img) * NN;
#pragma unroll
    for (int e = 0; e < 8; ++e) {
        int i = e * 64 + l;
        float v = 0.0f;
        if (i < 128 || i >= 384) {
            int y = (i + 128) & (GSZ - 1);
            float scy = kb_ft_inv((float)(y - 128) * (1.0f / (float)GSZ));
            v = xrow[y] * scx * scy;
        }
        int rev = (l & 7) * 64 + (l >> 3) * 8 + e;
        int ph = rev + (rev >> 3);
        re[w][ph] = v;
        im[w][ph] = 0.0f;
    }
    __syncthreads();
    radix8_stage<1>(re[w], im[w], l);
    __syncthreads();
    radix8_stage<8>(re[w], im[w], l);
    __syncthreads();
    radix8_stage<64>(re[w], im[w], l);
    __syncthreads();
    // fp16 output (x 2^24) into region A at row slot (r<128 ? r : r-256)
    __half2* pa = regA(grid, bc);
    int slot = (r < 128) ? r : r - 256;
    size_t abase = (size_t)slot * GSZ;
#pragma unroll
    for (int e = 0; e < 8; ++e) {
        int k = e * 64 + l;
        int ph = k + (k >> 3);
        pa[abase + k] = __float22half2_rn(
            make_float2(re[w][ph] * SSCALE, im[w][ph] * SSCALE));
    }
}

// ---------------- column FFT: fp16 in (region A), fp16 spectrum out (B) -----

#define CSTR 577
__global__ void __launch_bounds__(512) k_fft_col(float2* __restrict__ grid) {
    __shared__ float re[16][CSTR], im[16][CSTR];
    int b = blockIdx.x;
    int bc = b >> 5;
    int c0 = (b & 31) << 4;
    const __half2* pa = regA_c(grid, bc);
    int t = threadIdx.x;
#pragma unroll
    for (int it = 0; it < 16; ++it) {
        int idx = it * 512 + t;
        int row = idx >> 4, col = idx & 15;
        float2 v = make_float2(0.0f, 0.0f);
        if (row < 128)
            v = __half22float2(pa[(size_t)row * GSZ + c0 + col]);
        else if (row >= 384)
            v = __half22float2(pa[(size_t)(row - 256) * GSZ + c0 + col]);
        int rev = (row & 7) * 64 + ((row >> 3) & 7) * 8 + (row >> 6);
        int ph = rev + (rev >> 3);
        re[col][ph] = v.x;
        im[col][ph] = v.y;
    }
    __syncthreads();
    int col = t & 15, jg = t >> 4;   // jg in [0,32): 2 butterflies per thread
#pragma unroll
    for (int k = 0; k < 2; ++k) radix8_stage<1>(re[col], im[col], jg + 32 * k);
    __syncthreads();
#pragma unroll
    for (int k = 0; k < 2; ++k) radix8_stage<8>(re[col], im[col], jg + 32 * k);
    __syncthreads();
#pragma unroll
    for (int k = 0; k < 2; ++k) radix8_stage<64>(re[col], im[col], jg + 32 * k);
    __syncthreads();
    __half2* ghp = gh_plane(grid, bc);
#pragma unroll
    for (int it = 0; it < 16; ++it) {
        int idx = it * 512 + t;
        int row = idx >> 4, c = idx & 15;
        int ph = row + (row >> 3);
        // input already carried 2^24 -> no extra scale here
        ghp[(size_t)row * GSZ + c0 + c] =
            __float22half2_rn(make_float2(re[c][ph], im[c][ph]));
    }
}

// ---------------- table-driven fp16 oct gather (unchanged from round 15) ----

__global__ void __launch_bounds__(128, 6) k_gather_tile(
    const float2* __restrict__ grid, const unsigned* __restrict__ cnt,
    const unsigned* __restrict__ meta, const __half2* __restrict__ whalf,
    float2* __restrict__ out) {
    __shared__ __half2 ldsh[QPL * PLANE];   // 15456 B (total LDS)
    int bid = blockIdx.x;
    int b = ((bid & 7) << 8) | (bid >> 3);  // bijective XCD swizzle (2048 = 8*256)
    int tile = b >> 1;
    int oct = b & 1;
    int bc0 = oct * QPL;
    int tx0 = (tile >> 5) << 4;
    int ty0 = (tile & 31) << 4;
    int t = threadIdx.x;
#pragma unroll
    for (int k = 0; k < 28; ++k) {
        int idx = t + (k << 7);
        if (idx < NPQ) {
            int p = idx / (TRW * TRW);
            int rem = idx - p * (TRW * TRW);
            int r = rem / TRW;
            int c = rem - r * TRW;
            int row = (tx0 - 2 + r) & (GSZ - 1);
            int col = (ty0 - 2 + c) & (GSZ - 1);
            ldsh[p * PLANE + r * TPITCH + c] =
                gh_plane_c(grid, bc0 + p)[(size_t)row * GSZ + col];
        }
    }
    int n = (int)cnt[tile];
    if (n > CAP) n = CAP;
    __syncthreads();
    int g = t >> 6;                         // wave -> planes 4g..4g+3
    int base0 = (4 * g) * PLANE;
    int base1 = base0 + PLANE;
    int base2 = base1 + PLANE;
    int base3 = base2 + PLANE;
    int bcw = bc0 + 4 * g;
    for (int s = (t & 63); s < n; s += 64) {
        int idx = tile * CAP + s;
        unsigned mc = meta[idx];
        int m = (int)(mc >> 8);
        int lx = (int)((mc >> 4) & 15u);
        int ly = (int)(mc & 15u);
        const __half2* wp = whalf + (size_t)idx * 6;
        __half2 p0 = wp[0], p1 = wp[1], p2 = wp[2];
        __half2 q0 = wp[3], q1 = wp[4], q2 = wp[5];
        float w0v[6], w1v[6];
        w0v[0] = __low2float(p0) * INV_SSCALE;
        w0v[1] = __high2float(p0) * INV_SSCALE;
        w0v[2] = __low2float(p1) * INV_SSCALE;
        w0v[3] = __high2float(p1) * INV_SSCALE;
        w0v[4] = __low2float(p2) * INV_SSCALE;
        w0v[5] = __high2float(p2) * INV_SSCALE;
        w1v[0] = __low2float(q0);
        w1v[1] = __high2float(q0);
        w1v[2] = __low2float(q1);
        w1v[3] = __high2float(q1);
        w1v[4] = __low2float(q2);
        w1v[5] = __high2float(q2);
        int off0 = lx * TPITCH + ly;
        float ar0 = 0.f, ai0 = 0.f, ar1 = 0.f, ai1 = 0.f;
        float ar2 = 0.f, ai2 = 0.f, ar3 = 0.f, ai3 = 0.f;
#pragma unroll
        for (int ii = 0; ii < 6; ++ii) {
            float wi = w0v[ii];
            int rowoff = off0 + ii * TPITCH;
#pragma unroll
            for (int j = 0; j < 6; ++j) {
                float wv = wi * w1v[j];
                int o = rowoff + j;
                float2 v0 = __half22float2(ldsh[base0 + o]);
                float2 v1 = __half22float2(ldsh[base1 + o]);
                float2 v2 = __half22float2(ldsh[base2 + o]);
                float2 v3 = __half22float2(ldsh[base3 + o]);
                ar0 = fmaf(wv, v0.x, ar0);
                ai0 = fmaf(wv, v0.y, ai0);
                ar1 = fmaf(wv, v1.x, ar1);
                ai1 = fmaf(wv, v1.y, ai1);
                ar2 = fmaf(wv, v2.x, ar2);
                ai2 = fmaf(wv, v2.y, ai2);
                ar3 = fmaf(wv, v3.x, ar3);
                ai3 = fmaf(wv, v3.y, ai3);
            }
        }
        out[(size_t)(bcw + 0) * MM + m] = make_float2(ar0, ai0);
        out[(size_t)(bcw + 1) * MM + m] = make_float2(ar1, ai1);
        out[(size_t)(bcw + 2) * MM + m] = make_float2(ar2, ai2);
        out[(size_t)(bcw + 3) * MM + m] = make_float2(ar3, ai3);
    }
}

// Fallback gather (reads fp16 spectrum) if ws is too small for the tables.
__global__ void k_gather(const float2* __restrict__ grid, const float* __restrict__ kt,
                         float2* __restrict__ out) {
    int tid = blockIdx.x * blockDim.x + threadIdx.x;
    int m = tid & (MM - 1);
    int bc = tid >> 16;
    float tmx = kt[m] * KSCALE;
    float tmy = kt[MM + m] * KSCALE;
    float bx = floorf(tmx), by = floorf(tmy);
    int ibx = (int)bx, iby = (int)by;
    float w0[6], w1[6];
    int ix[6], iy[6];
#pragma unroll
    for (int o = 0; o < 6; ++o) {
        float offv = (float)(o - 2);
        w0[o] = kb_weight(tmx - (bx + offv)) * INV_SSCALE;
        w1[o] = kb_weight(tmy - (by + offv));
        ix[o] = (ibx + (o - 2) + GSZ) & (GSZ - 1);
        iy[o] = (iby + (o - 2) + GSZ) & (GSZ - 1);
    }
    const __half2* img = gh_plane_c(grid, bc);
    float ar = 0.0f, ai = 0.0f;
#pragma unroll
    for (int i = 0; i < 6; ++i) {
        const __half2* rowp = img + (size_t)ix[i] * GSZ;
        float wi = w0[i];
#pragma unroll
        for (int j = 0; j < 6; ++j) {
            float2 v = __half22float2(rowp[iy[j]]);
            float wv = wi * w1[j];
            ar = fmaf(wv, v.x, ar);
            ai = fmaf(wv, v.y, ai);
        }
    }
    out[(size_t)bc * MM + m] = make_float2(ar, ai);
}

// Standalone row FFT for the fallback path (no binning) — fp16 region-A out.
__global__ void __launch_bounds__(256) k_fft_row(const float* __restrict__ x,
                                                 float2* __restrict__ grid) {
    __shared__ float re[4][LDSP], im[4][LDSP];
    int b = blockIdx.x;
    int t = threadIdx.x;
    int w = t >> 6;
    int l = t & 63;
    int rg = (b & 63) * 4 + w;
    int bc = b >> 6;
    int r = (rg < 128) ? rg : rg + 256;
    int r_img = rg ^ 128;
    float scx = kb_ft_inv((float)(r_img - 128) * (1.0f / (float)GSZ));
    const float* xrow = x + ((size_t)bc * NN + (size_t)r_img) * NN;
#pragma unroll
    for (int e = 0; e < 8; ++e) {
        int i = e * 64 + l;
        float v = 0.0f;
        if (i < 128 || i >= 384) {
            int y = (i + 128) & (GSZ - 1);
            float scy = kb_ft_inv((float)(y - 128) * (1.0f / (float)GSZ));
            v = xrow[y] * scx * scy;
        }
        int rev = (l & 7) * 64 + (l >> 3) * 8 + e;
        int ph = rev + (rev >> 3);
        re[w][ph] = v;
        im[w][ph] = 0.0f;
    }
    __syncthreads();
    radix8_stage<1>(re[w], im[w], l);
    __syncthreads();
    radix8_stage<8>(re[w], im[w], l);
    __syncthreads();
    radix8_stage<64>(re[w], im[w], l);
    __syncthreads();
    __half2* pa = regA(grid, bc);
    int slot = (r < 128) ? r : r - 256;
    size_t abase = (size_t)slot * GSZ;
#pragma unroll
    for (int e = 0; e < 8; ++e) {
        int k = e * 64 + l;
        int ph = k + (k >> 3);
        pa[abase + k] = __float22half2_rn(
            make_float2(re[w][ph] * SSCALE, im[w][ph] * SSCALE));
    }
}

// ---------------- launch ----------------

extern "C" void kernel_launch(void* const* d_in, const int* in_sizes, int n_in,
                              void* d_out, int out_size, void* d_ws, size_t ws_size,
                              hipStream_t stream) {
    const float* x = (const float*)d_in[0];
    const float* kt = (const float*)d_in[1];
    float2* out = (float2*)d_out;
    char* ws = (char*)d_ws;

    const size_t GRID_BYTES = (size_t)BC * GG * sizeof(float2);      // 33,554,432
    const size_t CNT_BYTES = 1024 * sizeof(unsigned);                // 4,096
    const size_t META_BYTES = (size_t)1024 * CAP * sizeof(unsigned); // 589,824
    const size_t WH_BYTES = (size_t)1024 * CAP * 6 * sizeof(__half2);// 3,538,944
    float2* grid = (float2*)ws;
    unsigned* cnt = (unsigned*)(ws + GRID_BYTES);
    unsigned* meta = (unsigned*)(ws + GRID_BYTES + CNT_BYTES);
    __half2* whalf = (__half2*)(ws + GRID_BYTES + CNT_BYTES + META_BYTES);
    const size_t NEED = GRID_BYTES + CNT_BYTES + META_BYTES + WH_BYTES; // 37,687,296

    if (ws_size >= NEED) {
        hipMemsetAsync(cnt, 0, CNT_BYTES, stream);
        k_fft_row_bin<<<ROWBLK + 256, 256, 0, stream>>>(x, grid, kt, cnt, meta, whalf);
        k_fft_col<<<BC * (GSZ / 16), 512, 0, stream>>>(grid);
        k_gather_tile<<<2048, 128, 0, stream>>>(grid, cnt, meta, whalf, out);
    } else {
        k_fft_row<<<BC * 64, 256, 0, stream>>>(x, grid);
        k_fft_col<<<BC * (GSZ / 16), 512, 0, stream>>>(grid);
        k_gather<<<(BC * MM) / 256, 256, 0, stream>>>(grid, kt, out);
    }
}